// Round 1
// baseline (3434.514 us; speedup 1.0000x reference)
//
#include <hip/hip_runtime.h>
#include <math.h>

#define D 256
#define KC 64
#define NPTS 8192
#define TRI ((D*(D+1))/2)     // 32896 floats = 131584 B packed lower triangle

#define XS_PITCH 66           // pitch for p-major LDS tiles (bank-friendly, float2-aligned)
#define RED_PITCH 68

// ---------------------------------------------------------------------------
// Per-cluster preprocessing: Cholesky of var (lower L), in-place invert L,
// emit G^T (dense, zeros above diag), t = G*mu, bias = log(pi)+0.5*logdetP-0.5*|t|^2
// One block of 256 threads per cluster; packed triangle lives in LDS.
// ---------------------------------------------------------------------------
__global__ __launch_bounds__(256) void gmm_preproc(
    const float* __restrict__ var, const float* __restrict__ mu,
    const float* __restrict__ pi,
    float* __restrict__ Gt, float* __restrict__ tvec, float* __restrict__ bias)
{
  __shared__ float W[TRI];
  __shared__ float col[D];
  __shared__ float red[256];
  __shared__ float sdiag;
  const int k = blockIdx.x, tid = threadIdx.x;
  const float* A = var + (size_t)k * D * D;

  // load packed lower triangle
  for (int idx = tid; idx < TRI; idx += 256) {
    int i = (int)((sqrtf(8.0f * (float)idx + 1.0f) - 1.0f) * 0.5f);
    while ((i + 1) * (i + 2) / 2 <= idx) ++i;
    while (i * (i + 1) / 2 > idx) --i;
    int p = idx - i * (i + 1) / 2;
    W[idx] = A[i * D + p];
  }
  __syncthreads();

  // right-looking Cholesky (lower)
  for (int j = 0; j < D; ++j) {
    const int djidx = j * (j + 1) / 2 + j;
    if (tid == 0) sdiag = sqrtf(W[djidx]);
    __syncthreads();
    const float dj = sdiag;
    const int i = j + 1 + tid;
    float ci = 0.0f;
    int base = 0;
    if (i < D) {
      base = i * (i + 1) / 2;
      ci = W[base + j] / dj;
      W[base + j] = ci;
      col[i] = ci;
    }
    if (tid == 0) W[djidx] = dj;
    __syncthreads();
    if (i < D) {
      for (int l = j + 1; l <= i; ++l)
        W[base + l] -= ci * col[l];
    }
    __syncthreads();
  }

  // logdet(P) = -2 * sum log diag(L)
  red[tid] = logf(W[tid * (tid + 1) / 2 + tid]);
  __syncthreads();
  for (int s = 128; s > 0; s >>= 1) {
    if (tid < s) red[tid] += red[tid + s];
    __syncthreads();
  }
  const float logdetP = -2.0f * red[0];
  __syncthreads();

  // in-place inversion of lower-triangular L: W := L^{-1}
  // process columns right-to-left; trailing block already inverted
  for (int j = D - 1; j >= 0; --j) {
    const int p = j + 1 + tid;
    if (p < D) col[p] = W[p * (p + 1) / 2 + j];          // original L column j
    if (tid == 0) sdiag = W[j * (j + 1) / 2 + j];        // original L_jj
    __syncthreads();
    const float inv = 1.0f / sdiag;
    const int i = j + 1 + tid;
    if (i < D) {
      const int base = i * (i + 1) / 2;
      float s = 0.0f;
      for (int p2 = j + 1; p2 <= i; ++p2)
        s += W[base + p2] * col[p2];                     // Ginv(i,p2)*L(p2,j)
      W[base + j] = -inv * s;
    }
    if (tid == 0) W[j * (j + 1) / 2 + j] = inv;
    __syncthreads();
  }

  // t = G * mu (row dot), |t|^2 reduce, bias
  col[tid] = mu[k * D + tid];
  __syncthreads();
  float tv = 0.0f;
  {
    const int base = tid * (tid + 1) / 2;
    for (int p2 = 0; p2 <= tid; ++p2) tv += W[base + p2] * col[p2];
    tvec[k * D + tid] = tv;
  }
  red[tid] = tv * tv;
  __syncthreads();
  for (int s = 128; s > 0; s >>= 1) {
    if (tid < s) red[tid] += red[tid + s];
    __syncthreads();
  }
  if (tid == 0) bias[k] = logf(pi[k]) + 0.5f * logdetP - 0.5f * red[0];

  // write G transposed dense: Gt[k][p][i] = Linv[i][p] (0 when p > i)
  for (int idx = tid; idx < D * D; idx += 256) {
    const int p = idx >> 8, i2 = idx & 255;
    const float v = (p <= i2) ? W[i2 * (i2 + 1) / 2 + p] : 0.0f;
    Gt[(size_t)k * D * D + idx] = v;
  }
}

// ---------------------------------------------------------------------------
// Scoring: per block, 64 points x 32 clusters. y = G*x computed via p-major
// LDS tiles and 4n x 4i register outer products; score = bias + y.t - 0.5|y|^2.
// Deterministic tree reduction across i-groups; running argmax kept by
// threads 0..63 (one per point).
// ---------------------------------------------------------------------------
__global__ __launch_bounds__(256) void gmm_score(
    const float* __restrict__ x, const float* __restrict__ Gt,
    const float* __restrict__ tvec, const float* __restrict__ bias,
    float* __restrict__ part)
{
  __shared__ float xs[D * XS_PITCH];     // xs[p*66 + n], n in [0,64)
  __shared__ float gs[D * XS_PITCH];     // gs[p*66 + il], il in [0,64)
  __shared__ float ts[D];
  __shared__ float red2[16 * RED_PITCH];
  const int blk = blockIdx.x;
  const int ntile = blk & 127, kh = blk >> 7;
  const int tid = threadIdx.x;
  const int n0 = ntile * 64;

  // stage x tile transposed (p-major)
  for (int idx = tid; idx < 64 * D; idx += 256) {
    const int n = idx >> 8, p = idx & 255;
    xs[p * XS_PITCH + n] = x[(size_t)(n0 + n) * D + p];
  }

  const int ngrp = tid & 15, igrp = tid >> 4;
  const int na = ngrp * 4, ia4 = igrp * 4;
  float bestsc = -3.0e38f;
  int bestk = 0;

  for (int kk = 0; kk < 32; ++kk) {
    const int k = (kh << 5) + kk;
    ts[tid] = tvec[k * D + tid];
    float part_acc[4] = {0.f, 0.f, 0.f, 0.f};

    for (int ib = 0; ib < 4; ++ib) {
      const int I = ib << 6;
      const int plim = I + 64;          // triangular: G[i][p]=0 for p>i
      __syncthreads();                  // protect gs/xs/ts users of prev stage
      const float* gsrc = Gt + ((size_t)k * D) * D + I;
      for (int idx = tid; idx < (plim << 6); idx += 256) {
        const int p = idx >> 6, il = idx & 63;
        gs[p * XS_PITCH + il] = gsrc[p * D + il];
      }
      __syncthreads();

      float acc[4][4];
#pragma unroll
      for (int a = 0; a < 4; ++a)
#pragma unroll
        for (int b = 0; b < 4; ++b) acc[a][b] = 0.f;

      for (int p = 0; p < plim; ++p) {
        const float2 xv0 = *reinterpret_cast<const float2*>(&xs[p * XS_PITCH + na]);
        const float2 xv1 = *reinterpret_cast<const float2*>(&xs[p * XS_PITCH + na + 2]);
        const float2 gv0 = *reinterpret_cast<const float2*>(&gs[p * XS_PITCH + ia4]);
        const float2 gv1 = *reinterpret_cast<const float2*>(&gs[p * XS_PITCH + ia4 + 2]);
        const float xr[4] = {xv0.x, xv0.y, xv1.x, xv1.y};
        const float gr[4] = {gv0.x, gv0.y, gv1.x, gv1.y};
#pragma unroll
        for (int a = 0; a < 4; ++a)
#pragma unroll
          for (int b = 0; b < 4; ++b)
            acc[a][b] += xr[a] * gr[b];
      }

#pragma unroll
      for (int b = 0; b < 4; ++b) {
        const float tb = ts[I + ia4 + b];
#pragma unroll
        for (int a = 0; a < 4; ++a) {
          const float y = acc[a][b];
          part_acc[a] += y * (tb - 0.5f * y);   // y*t - 0.5*y^2
        }
      }
    }

    __syncthreads();
#pragma unroll
    for (int a = 0; a < 4; ++a)
      red2[igrp * RED_PITCH + na + a] = part_acc[a];
    __syncthreads();
    if (tid < 64) {
      float s = 0.f;
#pragma unroll
      for (int g = 0; g < 16; ++g) s += red2[g * RED_PITCH + tid];
      const float sc = bias[k] + s;
      if (sc > bestsc) { bestsc = sc; bestk = k; }   // strict > keeps first max
    }
  }

  if (tid < 64) {
    const size_t o = ((size_t)kh * NPTS + n0 + tid) * 2;
    part[o] = bestsc;
    part[o + 1] = __int_as_float(bestk);
  }
}

// ---------------------------------------------------------------------------
// Merge the two k-halves; tie prefers the lower k (half 0), matching
// jnp.argmax first-occurrence semantics.
// ---------------------------------------------------------------------------
__global__ __launch_bounds__(256) void gmm_merge(
    const float* __restrict__ part, int* __restrict__ out)
{
  const int n = blockIdx.x * 256 + threadIdx.x;
  const float s0 = part[(size_t)n * 2];
  const int k0 = __float_as_int(part[(size_t)n * 2 + 1]);
  const float s1 = part[((size_t)NPTS + n) * 2];
  const int k1 = __float_as_int(part[((size_t)NPTS + n) * 2 + 1]);
  out[n] = (s1 > s0) ? k1 : k0;
}

extern "C" void kernel_launch(void* const* d_in, const int* in_sizes, int n_in,
                              void* d_out, int out_size, void* d_ws, size_t ws_size,
                              hipStream_t stream)
{
  const float* x   = (const float*)d_in[0];   // (8192, 256)
  const float* mu  = (const float*)d_in[1];   // (64, 256)
  const float* var = (const float*)d_in[2];   // (64, 256, 256)
  const float* pi  = (const float*)d_in[3];   // (64,)

  char* ws = (char*)d_ws;
  float* Gt   = (float*)ws;                                   // K*D*D floats
  float* tvec = (float*)(ws + (size_t)KC * D * D * sizeof(float));
  float* bias = tvec + (size_t)KC * D;
  float* part = bias + KC;                                    // 2*N*2 floats
  int* out = (int*)d_out;

  gmm_preproc<<<KC, 256, 0, stream>>>(var, mu, pi, Gt, tvec, bias);
  gmm_score<<<256, 256, 0, stream>>>(x, Gt, tvec, bias, part);
  gmm_merge<<<NPTS / 256, 256, 0, stream>>>(part, out);
}

// Round 3
// 2700.838 us; speedup vs baseline: 1.2716x; 1.2716x over previous
//
#include <hip/hip_runtime.h>
#include <math.h>

#define D 256
#define KC 64
#define NPTS 8192
#define TRI ((D*(D+1))/2)

#define WSZ 33024             // odd-padded packed triangle size (floats)
#define XS_PITCH 66           // pitch for p-major LDS tiles (bank-friendly, float2-aligned)
#define RED_PITCH 68

__device__ __forceinline__ int wb(int r) { return (r*(r+1))/2 + (r>>1); }  // odd-padded row base
__device__ __forceinline__ int tb(int r) { return (r*(r+1))/2; }           // plain packed base

// ---------------------------------------------------------------------------
// Per-cluster preprocessing, blocked (B=64):
//   phase 1: blocked Cholesky (diag factor via wave-sync register/shfl scheme,
//            U=inv(L11) per panel, TRSM via U, SYRK trailing update)
//   phase 2: blocked in-place triangular inversion G = L^{-1}
//   phase 3: t = G*mu, bias, dense G^T write-out
// U blocks are staged in the (not yet written) Gt slab of this cluster.
// ---------------------------------------------------------------------------
__global__ __launch_bounds__(256) void gmm_preproc(
    const float* __restrict__ var, const float* __restrict__ mu,
    const float* __restrict__ pi,
    float* __restrict__ Gt, float* __restrict__ tvec, float* __restrict__ bias)
{
  __shared__ float W[WSZ];        // packed lower triangle, odd-padded rows
  __shared__ float Ubuf[2080];    // packed 64x64 lower triangle (current U block)
  __shared__ float Tbuf[64*65];   // dense 64x64 scratch, pitch 65
  __shared__ float colbuf[D];
  __shared__ float red[256];

  const int k = blockIdx.x, tid = threadIdx.x;
  const int lane = tid & 63, wid = tid >> 6;
  const float* A = var + (size_t)k*D*D;
  float* Ug = Gt + (size_t)k*D*D;   // U scratch (first 8320 floats of this cluster's Gt slab)

  // ---- load packed lower triangle ----
  for (int idx = tid; idx < TRI; idx += 256) {
    int i = (int)((sqrtf(8.0f*(float)idx + 1.0f) - 1.0f)*0.5f);
    while ((i+1)*(i+2)/2 <= idx) ++i;
    while (i*(i+1)/2 > idx) --i;
    const int p = idx - i*(i+1)/2;
    W[wb(i) + p] = A[i*D + p];
  }
  __syncthreads();

  // ---- phase 1: blocked Cholesky ----
  for (int jb = 0; jb < 4; ++jb) {
    const int c0 = jb*64, c1 = c0 + 64, m = 256 - c1;

    // diag factor: wave 0, lane = row within block. Only own-row LDS accesses;
    // the running diagonal lives in a register and is broadcast via shfl.
    if (wid == 0) {
      const int rbase = wb(c0 + lane) + c0;
      float dreg = W[rbase + lane];
      for (int j = 0; j < 64; ++j) {
        const float dj = sqrtf(__shfl(dreg, j, 64));
        const float dinv = 1.0f / dj;
        float c = 0.0f;
        if (lane > j)       { c = W[rbase + j]*dinv; W[rbase + j] = c; }
        else if (lane == j) { W[rbase + j] = dj; }
        for (int p = j + 1; p <= lane; ++p) {      // own-row trailing update
          const float cp = __shfl(c, p, 64);
          const float v = W[rbase + p] - c*cp;
          W[rbase + p] = v;
          if (p == lane) dreg = v;
        }
      }
    }
    __syncthreads();

    // U = inv(L11): wave 0, lane = column j (reads L written before the barrier)
    if (wid == 0) {
      const int j = lane;
      Ubuf[tb(j) + j] = 1.0f / W[wb(c0 + j) + c0 + j];
      for (int i = j + 1; i < 64; ++i) {
        const int rb2 = wb(c0 + i) + c0;
        float s = 0.0f;
        for (int p = j; p < i; ++p)
          s += W[rb2 + p] * Ubuf[tb(p) + j];
        Ubuf[tb(i) + j] = -s / W[rb2 + i];
      }
    }
    __syncthreads();

    // publish U: global scratch + overwrite diag block of W with U (= G_II)
    for (int idx = tid; idx < 2080; idx += 256) {
      const float u = Ubuf[idx];
      Ug[jb*2080 + idx] = u;
      int i = (int)((sqrtf(8.0f*(float)idx + 1.0f) - 1.0f)*0.5f);
      while ((i+1)*(i+2)/2 <= idx) ++i;
      while (i*(i+1)/2 > idx) --i;
      const int p = idx - i*(i+1)/2;
      W[wb(c0 + i) + c0 + p] = u;
    }
    __syncthreads();

    // TRSM: rows below panel, L21 = A21 * U^T (in place, descending j)
    if (tid < m) {
      const int rb3 = wb(c1 + tid) + c0;
      for (int j = 63; j >= 0; --j) {
        const int ub = tb(j);
        float s = 0.0f;
        for (int p = 0; p <= j; ++p)
          s += W[rb3 + p] * Ubuf[ub + p];
        W[rb3 + j] = s;
      }
    }
    __syncthreads();

    // SYRK: trailing triangle -= L21 * L21^T (4x4 tiles over flat tile index)
    if (m > 0) {
      const int nt = m >> 2, ntri = nt*(nt+1)/2;
      for (int tau = tid; tau < ntri; tau += 256) {
        int ti = (int)((sqrtf(8.0f*(float)tau + 1.0f) - 1.0f)*0.5f);
        while ((ti+1)*(ti+2)/2 <= tau) ++ti;
        while (ti*(ti+1)/2 > tau) --ti;
        const int tl = tau - ti*(ti+1)/2;
        const int i0 = c1 + ti*4, l0 = c1 + tl*4;
        const int ib[4] = {wb(i0), wb(i0+1), wb(i0+2), wb(i0+3)};
        const int lb[4] = {wb(l0), wb(l0+1), wb(l0+2), wb(l0+3)};
        float acc[4][4];
#pragma unroll
        for (int a = 0; a < 4; ++a)
#pragma unroll
          for (int b = 0; b < 4; ++b) acc[a][b] = 0.0f;
        for (int p = 0; p < 64; ++p) {
          const int cp = c0 + p;
          float av[4], bv[4];
#pragma unroll
          for (int a = 0; a < 4; ++a) av[a] = W[ib[a] + cp];
#pragma unroll
          for (int b = 0; b < 4; ++b) bv[b] = W[lb[b] + cp];
#pragma unroll
          for (int a = 0; a < 4; ++a)
#pragma unroll
            for (int b = 0; b < 4; ++b) acc[a][b] += av[a]*bv[b];
        }
#pragma unroll
        for (int a = 0; a < 4; ++a)
#pragma unroll
          for (int b = 0; b < 4; ++b) {
            const int rr = i0 + a, cc = l0 + b;
            if (cc <= rr) W[ib[a] + cc] -= acc[a][b];
          }
      }
    }
    __syncthreads();
  }

  // ---- phase 2: blocked in-place inversion G = L^{-1} ----
  // G_IJ = -U_I * (sum_{K=J}^{I-1} L_IK * G_KJ); J ascending, I ascending.
  // Diag blocks already hold U (=G_II); K=J term reads them with j<=p masking.
  const int ti2 = tid >> 4, tj2 = tid & 15;
  const int i0g = ti2*4, j0g = tj2*4;
  for (int J = 0; J < 3; ++J) {
    for (int I = J + 1; I < 4; ++I) {
      for (int idx = tid; idx < 2080; idx += 256)
        Ubuf[idx] = Ug[I*2080 + idx];
      __syncthreads();

      float acc[4][4];
#pragma unroll
      for (int q = 0; q < 4; ++q)
#pragma unroll
        for (int r = 0; r < 4; ++r) acc[q][r] = 0.0f;
      for (int K = J; K < I; ++K) {
        const int arow = 64*I, brow = 64*K;
        const bool dK = (K == J);
        for (int p = 0; p < 64; ++p) {
          float av[4], bv[4];
#pragma unroll
          for (int q = 0; q < 4; ++q) av[q] = W[wb(arow + i0g + q) + 64*K + p];
#pragma unroll
          for (int r = 0; r < 4; ++r) {
            const float raw = W[wb(brow + p) + 64*J + j0g + r];
            bv[r] = (dK && (j0g + r > p)) ? 0.0f : raw;
          }
#pragma unroll
          for (int q = 0; q < 4; ++q)
#pragma unroll
            for (int r = 0; r < 4; ++r) acc[q][r] += av[q]*bv[r];
        }
      }
#pragma unroll
      for (int q = 0; q < 4; ++q)
#pragma unroll
        for (int r = 0; r < 4; ++r) Tbuf[(i0g+q)*65 + j0g + r] = acc[q][r];
      __syncthreads();

      float g[4][4];
#pragma unroll
      for (int q = 0; q < 4; ++q)
#pragma unroll
        for (int r = 0; r < 4; ++r) g[q][r] = 0.0f;
      for (int p = 0; p < 64; ++p) {
        float uv[4], tv4[4];
#pragma unroll
        for (int q = 0; q < 4; ++q) {
          const int ir = i0g + q;
          uv[q] = (p <= ir) ? Ubuf[tb(ir) + p] : 0.0f;
        }
#pragma unroll
        for (int r = 0; r < 4; ++r) tv4[r] = Tbuf[p*65 + j0g + r];
#pragma unroll
        for (int q = 0; q < 4; ++q)
#pragma unroll
          for (int r = 0; r < 4; ++r) g[q][r] += uv[q]*tv4[r];
      }
      __syncthreads();   // all Tbuf/Ubuf reads done before W_IJ overwrite
#pragma unroll
      for (int q = 0; q < 4; ++q)
#pragma unroll
        for (int r = 0; r < 4; ++r)
          W[wb(64*I + i0g + q) + 64*J + j0g + r] = -g[q][r];
      // next iteration's post-load barrier orders these writes vs. reads
    }
  }
  __syncthreads();

  // ---- phase 3: t = G*mu, bias, Gt write-out ----
  colbuf[tid] = mu[k*D + tid];
  __syncthreads();
  {
    const int rb4 = wb(tid);
    float s = 0.0f;
    for (int p = 0; p <= tid; ++p) s += W[rb4 + p]*colbuf[p];
    tvec[k*D + tid] = s;
    red[tid] = s*s;
  }
  __syncthreads();
  for (int st = 128; st > 0; st >>= 1) { if (tid < st) red[tid] += red[tid+st]; __syncthreads(); }
  const float t2 = red[0];
  __syncthreads();
  red[tid] = logf(W[wb(tid) + tid]);   // log G_jj = -log L_jj; 0.5*logdetP = sum log G_jj
  __syncthreads();
  for (int st = 128; st > 0; st >>= 1) { if (tid < st) red[tid] += red[tid+st]; __syncthreads(); }
  if (tid == 0) bias[k] = logf(pi[k]) + red[0] - 0.5f*t2;
  __syncthreads();

  for (int idx = tid; idx < D*D; idx += 256) {   // Gt[k][p][i] = G[i][p]
    const int p = idx >> 8, i2 = idx & 255;
    Gt[(size_t)k*D*D + idx] = (p <= i2) ? W[wb(i2) + p] : 0.0f;
  }
}

// ---------------------------------------------------------------------------
// Scoring: per block, 64 points x 32 clusters. y = G*x computed via p-major
// LDS tiles and 4n x 4i register outer products; score = bias + y.t - 0.5|y|^2.
// ---------------------------------------------------------------------------
__global__ __launch_bounds__(256) void gmm_score(
    const float* __restrict__ x, const float* __restrict__ Gt,
    const float* __restrict__ tvec, const float* __restrict__ bias,
    float* __restrict__ part)
{
  __shared__ float xs[D * XS_PITCH];     // xs[p*66 + n], n in [0,64)
  __shared__ float gs[D * XS_PITCH];     // gs[p*66 + il], il in [0,64)
  __shared__ float ts[D];
  __shared__ float red2[16 * RED_PITCH];
  const int blk = blockIdx.x;
  const int ntile = blk & 127, kh = blk >> 7;
  const int tid = threadIdx.x;
  const int n0 = ntile * 64;

  for (int idx = tid; idx < 64 * D; idx += 256) {
    const int n = idx >> 8, p = idx & 255;
    xs[p * XS_PITCH + n] = x[(size_t)(n0 + n) * D + p];
  }

  const int ngrp = tid & 15, igrp = tid >> 4;
  const int na = ngrp * 4, ia4 = igrp * 4;
  float bestsc = -3.0e38f;
  int bestk = 0;

  for (int kk = 0; kk < 32; ++kk) {
    const int k = (kh << 5) + kk;
    ts[tid] = tvec[k * D + tid];
    float part_acc[4] = {0.f, 0.f, 0.f, 0.f};

    for (int ib = 0; ib < 4; ++ib) {
      const int I = ib << 6;
      const int plim = I + 64;          // triangular: G[i][p]=0 for p>i
      __syncthreads();
      const float* gsrc = Gt + ((size_t)k * D) * D + I;
      for (int idx = tid; idx < (plim << 6); idx += 256) {
        const int p = idx >> 6, il = idx & 63;
        gs[p * XS_PITCH + il] = gsrc[p * D + il];
      }
      __syncthreads();

      float acc[4][4];
#pragma unroll
      for (int a = 0; a < 4; ++a)
#pragma unroll
        for (int b = 0; b < 4; ++b) acc[a][b] = 0.f;

      for (int p = 0; p < plim; ++p) {
        const float2 xv0 = *reinterpret_cast<const float2*>(&xs[p * XS_PITCH + na]);
        const float2 xv1 = *reinterpret_cast<const float2*>(&xs[p * XS_PITCH + na + 2]);
        const float2 gv0 = *reinterpret_cast<const float2*>(&gs[p * XS_PITCH + ia4]);
        const float2 gv1 = *reinterpret_cast<const float2*>(&gs[p * XS_PITCH + ia4 + 2]);
        const float xr[4] = {xv0.x, xv0.y, xv1.x, xv1.y};
        const float gr[4] = {gv0.x, gv0.y, gv1.x, gv1.y};
#pragma unroll
        for (int a = 0; a < 4; ++a)
#pragma unroll
          for (int b = 0; b < 4; ++b)
            acc[a][b] += xr[a] * gr[b];
      }

#pragma unroll
      for (int b = 0; b < 4; ++b) {
        const float tb_ = ts[I + ia4 + b];
#pragma unroll
        for (int a = 0; a < 4; ++a) {
          const float y = acc[a][b];
          part_acc[a] += y * (tb_ - 0.5f * y);
        }
      }
    }

    __syncthreads();
#pragma unroll
    for (int a = 0; a < 4; ++a)
      red2[igrp * RED_PITCH + na + a] = part_acc[a];
    __syncthreads();
    if (tid < 64) {
      float s = 0.f;
#pragma unroll
      for (int g = 0; g < 16; ++g) s += red2[g * RED_PITCH + tid];
      const float sc = bias[k] + s;
      if (sc > bestsc) { bestsc = sc; bestk = k; }
    }
  }

  if (tid < 64) {
    const size_t o = ((size_t)kh * NPTS + n0 + tid) * 2;
    part[o] = bestsc;
    part[o + 1] = __int_as_float(bestk);
  }
}

__global__ __launch_bounds__(256) void gmm_merge(
    const float* __restrict__ part, int* __restrict__ out)
{
  const int n = blockIdx.x * 256 + threadIdx.x;
  const float s0 = part[(size_t)n * 2];
  const int k0 = __float_as_int(part[(size_t)n * 2 + 1]);
  const float s1 = part[((size_t)NPTS + n) * 2];
  const int k1 = __float_as_int(part[((size_t)NPTS + n) * 2 + 1]);
  out[n] = (s1 > s0) ? k1 : k0;
}

extern "C" void kernel_launch(void* const* d_in, const int* in_sizes, int n_in,
                              void* d_out, int out_size, void* d_ws, size_t ws_size,
                              hipStream_t stream)
{
  const float* x   = (const float*)d_in[0];   // (8192, 256)
  const float* mu  = (const float*)d_in[1];   // (64, 256)
  const float* var = (const float*)d_in[2];   // (64, 256, 256)
  const float* pi  = (const float*)d_in[3];   // (64,)

  char* ws = (char*)d_ws;
  float* Gt   = (float*)ws;                                   // K*D*D floats
  float* tvec = (float*)(ws + (size_t)KC * D * D * sizeof(float));
  float* bias = tvec + (size_t)KC * D;
  float* part = bias + KC;                                    // 2*N*2 floats
  int* out = (int*)d_out;

  gmm_preproc<<<KC, 256, 0, stream>>>(var, mu, pi, Gt, tvec, bias);
  gmm_score<<<256, 256, 0, stream>>>(x, Gt, tvec, bias, part);
  gmm_merge<<<NPTS / 256, 256, 0, stream>>>(part, out);
}

// Round 6
// 1748.974 us; speedup vs baseline: 1.9637x; 1.5442x over previous
//
#include <hip/hip_runtime.h>
#include <math.h>

#define D 256
#define KC 64
#define NPTS 8192
#define TRI ((D*(D+1))/2)

#define WSZ 33024             // odd-padded packed triangle size (floats)
#define XS_PITCH 66           // pitch for p-major LDS tiles (bank-friendly, float2-aligned)
#define RED_PITCH 68

__device__ __forceinline__ int wb(int r) { return (r*(r+1))/2 + (r>>1); }  // odd-padded row base

// ---------------------------------------------------------------------------
// Per-cluster preprocessing, blocked (B=64), register-resident serial core:
//   per panel: wave0 factors the 64x64 diag block entirely in registers
//   (row-per-lane, readlane broadcasts) and produces G11 = inv(L11) in the
//   same scheme; U staged dense in Tbuf; TRSM = register-row x broadcast-U;
//   SYRK = 4x4 LDS tiles (unchanged). Then blocked triangular inversion
//   (U blocks read from W diag in place) and t/bias/Gt emission.
// ---------------------------------------------------------------------------
__global__ __launch_bounds__(256, 1) void gmm_preproc(
    const float* __restrict__ var, const float* __restrict__ mu,
    const float* __restrict__ pi,
    float* __restrict__ Gt, float* __restrict__ tvec, float* __restrict__ bias)
{
  __shared__ float W[WSZ];        // packed lower triangle, odd-padded rows
  __shared__ float Tbuf[64*65];   // phase1: dense zero-padded U; phase2: T scratch
  __shared__ float colbuf[D];
  __shared__ float red[256];

  const int k = blockIdx.x, tid = threadIdx.x;
  const int lane = tid & 63, wid = tid >> 6;
  const float* A = var + (size_t)k*D*D;

  // ---- load packed lower triangle ----
  for (int idx = tid; idx < TRI; idx += 256) {
    int i = (int)((sqrtf(8.0f*(float)idx + 1.0f) - 1.0f)*0.5f);
    while ((i+1)*(i+2)/2 <= idx) ++i;
    while (i*(i+1)/2 > idx) --i;
    const int p = idx - i*(i+1)/2;
    W[wb(i) + p] = A[i*D + p];
  }
  __syncthreads();

  // ---- phase 1: blocked Cholesky, register-resident diag core ----
#pragma unroll 1
  for (int jb = 0; jb < 4; ++jb) {
    const int c0 = jb*64, c1 = c0 + 64, m = 256 - c1;

    if (wid == 0) {
      const int rbase = wb(c0 + lane) + c0;
      float Lrow[64];
#pragma unroll
      for (int p = 0; p < 64; ++p) Lrow[p] = W[rbase + p];   // p>lane: garbage, never escapes

      // fused in-register Cholesky of the 64x64 block (row per lane)
      float mydinv = 0.0f;
#pragma unroll
      for (int j = 0; j < 64; ++j) {
        const float dj = sqrtf(__shfl(Lrow[j], j, 64));
        const float dinv = 1.0f / dj;
        const float c = Lrow[j] * dinv;           // valid for lane > j
        Lrow[j] = (lane == j) ? dj : c;
        mydinv = (lane == j) ? dinv : mydinv;
#pragma unroll
        for (int p = j + 1; p < 64; ++p) {
          const float cp = __shfl(c, p, 64);      // lane p's c (readlane)
          Lrow[p] -= c * cp;                      // i==p updates diagonal; i<p garbage
        }
      }

      // G11 = inv(L11), forward substitution, rows finalized in lane order.
      // Grow doubles as the accumulator acc[j] until lane's own step.
      float Grow[64];
#pragma unroll
      for (int j = 0; j < 64; ++j) Grow[j] = 0.0f;
#pragma unroll
      for (int p = 0; p < 64; ++p) {
        // finalize lane p: G[p][j] = (delta_pj - acc[j]) / L[p][p]
#pragma unroll
        for (int j = 0; j <= p; ++j) {
          const float fin = (((j == p) ? 1.0f : 0.0f) - Grow[j]) * mydinv;
          Grow[j] = (lane == p) ? fin : Grow[j];
        }
        const float lp = (lane > p) ? Lrow[p] : 0.0f;   // mask: only i>p accumulate
#pragma unroll
        for (int j = 0; j <= p; ++j) {
          const float gpj = __shfl(Grow[j], p, 64);     // lane p's finalized G[p][j]
          Grow[j] += lp * gpj;
        }
      }

      // publish G11: packed W diag block (j<=lane) + dense zero-padded Tbuf
#pragma unroll
      for (int j = 0; j < 64; ++j) {
        if (j <= lane) W[rbase + j] = Grow[j];
        Tbuf[lane*65 + j] = (j <= lane) ? Grow[j] : 0.0f;
      }
    }
    __syncthreads();

    // TRSM: L21 = A21 * U^T. Thread = row (register-resident), U via uniform
    // LDS broadcasts from dense zero-padded Tbuf (no triangle logic).
    if (tid < m) {
      const int rb = wb(c1 + tid) + c0;
      float row[64];
#pragma unroll
      for (int p = 0; p < 64; ++p) row[p] = W[rb + p];
      for (int j = 0; j < 64; ++j) {
        const float* up = &Tbuf[j*65];
        float a0 = 0.f, a1 = 0.f, a2 = 0.f, a3 = 0.f;
#pragma unroll
        for (int p = 0; p < 64; p += 4) {
          a0 += row[p]   * up[p];
          a1 += row[p+1] * up[p+1];
          a2 += row[p+2] * up[p+2];
          a3 += row[p+3] * up[p+3];
        }
        W[rb + j] = (a0 + a1) + (a2 + a3);
      }
    }
    __syncthreads();

    // SYRK: trailing triangle -= L21 * L21^T (4x4 tiles over flat tile index)
    if (m > 0) {
      const int nt = m >> 2, ntri = nt*(nt+1)/2;
      for (int tau = tid; tau < ntri; tau += 256) {
        int ti = (int)((sqrtf(8.0f*(float)tau + 1.0f) - 1.0f)*0.5f);
        while ((ti+1)*(ti+2)/2 <= tau) ++ti;
        while (ti*(ti+1)/2 > tau) --ti;
        const int tl = tau - ti*(ti+1)/2;
        const int i0 = c1 + ti*4, l0 = c1 + tl*4;
        const int ib[4] = {wb(i0), wb(i0+1), wb(i0+2), wb(i0+3)};
        const int lb[4] = {wb(l0), wb(l0+1), wb(l0+2), wb(l0+3)};
        float acc[4][4];
#pragma unroll
        for (int a = 0; a < 4; ++a)
#pragma unroll
          for (int b = 0; b < 4; ++b) acc[a][b] = 0.0f;
        for (int p = 0; p < 64; ++p) {
          const int cp = c0 + p;
          float av[4], bv[4];
#pragma unroll
          for (int a = 0; a < 4; ++a) av[a] = W[ib[a] + cp];
#pragma unroll
          for (int b = 0; b < 4; ++b) bv[b] = W[lb[b] + cp];
#pragma unroll
          for (int a = 0; a < 4; ++a)
#pragma unroll
            for (int b = 0; b < 4; ++b) acc[a][b] += av[a]*bv[b];
        }
#pragma unroll
        for (int a = 0; a < 4; ++a)
#pragma unroll
          for (int b = 0; b < 4; ++b) {
            const int rr = i0 + a, cc = l0 + b;
            if (cc <= rr) W[ib[a] + cc] -= acc[a][b];
          }
      }
    }
    __syncthreads();
  }

  // ---- phase 2: blocked in-place inversion G = L^{-1} ----
  // G_IJ = -U_I * (sum_{K=J}^{I-1} L_IK * G_KJ); diag blocks of W hold U.
  const int ti2 = tid >> 4, tj2 = tid & 15;
  const int i0g = ti2*4, j0g = tj2*4;
#pragma unroll 1
  for (int J = 0; J < 3; ++J) {
#pragma unroll 1
    for (int I = J + 1; I < 4; ++I) {
      float acc[4][4];
#pragma unroll
      for (int q = 0; q < 4; ++q)
#pragma unroll
        for (int r = 0; r < 4; ++r) acc[q][r] = 0.0f;
      for (int K = J; K < I; ++K) {
        const int arow = 64*I, brow = 64*K;
        const bool dK = (K == J);
        for (int p = 0; p < 64; ++p) {
          float av[4], bv[4];
#pragma unroll
          for (int q = 0; q < 4; ++q) av[q] = W[wb(arow + i0g + q) + 64*K + p];
#pragma unroll
          for (int r = 0; r < 4; ++r) {
            const float raw = W[wb(brow + p) + 64*J + j0g + r];
            bv[r] = (dK && (j0g + r > p)) ? 0.0f : raw;
          }
#pragma unroll
          for (int q = 0; q < 4; ++q)
#pragma unroll
            for (int r = 0; r < 4; ++r) acc[q][r] += av[q]*bv[r];
        }
      }
#pragma unroll
      for (int q = 0; q < 4; ++q)
#pragma unroll
        for (int r = 0; r < 4; ++r) Tbuf[(i0g+q)*65 + j0g + r] = acc[q][r];
      __syncthreads();

      // G_IJ = -U_I * T ; U_I read from W diag block (p<=row mask)
      float g[4][4];
#pragma unroll
      for (int q = 0; q < 4; ++q)
#pragma unroll
        for (int r = 0; r < 4; ++r) g[q][r] = 0.0f;
      for (int p = 0; p < 64; ++p) {
        float uv[4], tv4[4];
#pragma unroll
        for (int q = 0; q < 4; ++q) {
          const int ir = i0g + q;
          uv[q] = (p <= ir) ? W[wb(64*I + ir) + 64*I + p] : 0.0f;
        }
#pragma unroll
        for (int r = 0; r < 4; ++r) tv4[r] = Tbuf[p*65 + j0g + r];
#pragma unroll
        for (int q = 0; q < 4; ++q)
#pragma unroll
          for (int r = 0; r < 4; ++r) g[q][r] += uv[q]*tv4[r];
      }
      __syncthreads();   // Tbuf reads done before W_IJ overwrite
#pragma unroll
      for (int q = 0; q < 4; ++q)
#pragma unroll
        for (int r = 0; r < 4; ++r)
          W[wb(64*I + i0g + q) + 64*J + j0g + r] = -g[q][r];
      __syncthreads();   // W_IJ visible before next iteration's reads
    }
  }

  // ---- phase 3: t = G*mu, bias, Gt write-out ----
  colbuf[tid] = mu[k*D + tid];
  __syncthreads();
  {
    const int rb4 = wb(tid);
    float s = 0.0f;
    for (int p = 0; p <= tid; ++p) s += W[rb4 + p]*colbuf[p];
    tvec[k*D + tid] = s;
    red[tid] = s*s;
  }
  __syncthreads();
  for (int st = 128; st > 0; st >>= 1) { if (tid < st) red[tid] += red[tid+st]; __syncthreads(); }
  const float t2 = red[0];
  __syncthreads();
  red[tid] = logf(W[wb(tid) + tid]);   // log G_jj; 0.5*logdetP = sum log G_jj
  __syncthreads();
  for (int st = 128; st > 0; st >>= 1) { if (tid < st) red[tid] += red[tid+st]; __syncthreads(); }
  if (tid == 0) bias[k] = logf(pi[k]) + red[0] - 0.5f*t2;
  __syncthreads();

  for (int idx = tid; idx < D*D; idx += 256) {   // Gt[k][p][i] = G[i][p]
    const int p = idx >> 8, i2 = idx & 255;
    Gt[(size_t)k*D*D + idx] = (p <= i2) ? W[wb(i2) + p] : 0.0f;
  }
}

// ---------------------------------------------------------------------------
// Scoring: per block, 64 points x 32 clusters. y = G*x computed via p-major
// LDS tiles and 4n x 4i register outer products; score = bias + y.t - 0.5|y|^2.
// ---------------------------------------------------------------------------
__global__ __launch_bounds__(256) void gmm_score(
    const float* __restrict__ x, const float* __restrict__ Gt,
    const float* __restrict__ tvec, const float* __restrict__ bias,
    float* __restrict__ part)
{
  __shared__ float xs[D * XS_PITCH];     // xs[p*66 + n], n in [0,64)
  __shared__ float gs[D * XS_PITCH];     // gs[p*66 + il], il in [0,64)
  __shared__ float ts[D];
  __shared__ float red2[16 * RED_PITCH];
  const int blk = blockIdx.x;
  const int ntile = blk & 127, kh = blk >> 7;
  const int tid = threadIdx.x;
  const int n0 = ntile * 64;

  for (int idx = tid; idx < 64 * D; idx += 256) {
    const int n = idx >> 8, p = idx & 255;
    xs[p * XS_PITCH + n] = x[(size_t)(n0 + n) * D + p];
  }

  const int ngrp = tid & 15, igrp = tid >> 4;
  const int na = ngrp * 4, ia4 = igrp * 4;
  float bestsc = -3.0e38f;
  int bestk = 0;

  for (int kk = 0; kk < 32; ++kk) {
    const int k = (kh << 5) + kk;
    ts[tid] = tvec[k * D + tid];
    float part_acc[4] = {0.f, 0.f, 0.f, 0.f};

    for (int ib = 0; ib < 4; ++ib) {
      const int I = ib << 6;
      const int plim = I + 64;          // triangular: G[i][p]=0 for p>i
      __syncthreads();
      const float* gsrc = Gt + ((size_t)k * D) * D + I;
      for (int idx = tid; idx < (plim << 6); idx += 256) {
        const int p = idx >> 6, il = idx & 63;
        gs[p * XS_PITCH + il] = gsrc[p * D + il];
      }
      __syncthreads();

      float acc[4][4];
#pragma unroll
      for (int a = 0; a < 4; ++a)
#pragma unroll
        for (int b = 0; b < 4; ++b) acc[a][b] = 0.f;

      for (int p = 0; p < plim; ++p) {
        const float2 xv0 = *reinterpret_cast<const float2*>(&xs[p * XS_PITCH + na]);
        const float2 xv1 = *reinterpret_cast<const float2*>(&xs[p * XS_PITCH + na + 2]);
        const float2 gv0 = *reinterpret_cast<const float2*>(&gs[p * XS_PITCH + ia4]);
        const float2 gv1 = *reinterpret_cast<const float2*>(&gs[p * XS_PITCH + ia4 + 2]);
        const float xr[4] = {xv0.x, xv0.y, xv1.x, xv1.y};
        const float gr[4] = {gv0.x, gv0.y, gv1.x, gv1.y};
#pragma unroll
        for (int a = 0; a < 4; ++a)
#pragma unroll
          for (int b = 0; b < 4; ++b)
            acc[a][b] += xr[a] * gr[b];
      }

#pragma unroll
      for (int b = 0; b < 4; ++b) {
        const float tb_ = ts[I + ia4 + b];
#pragma unroll
        for (int a = 0; a < 4; ++a) {
          const float y = acc[a][b];
          part_acc[a] += y * (tb_ - 0.5f * y);
        }
      }
    }

    __syncthreads();
#pragma unroll
    for (int a = 0; a < 4; ++a)
      red2[igrp * RED_PITCH + na + a] = part_acc[a];
    __syncthreads();
    if (tid < 64) {
      float s = 0.f;
#pragma unroll
      for (int g = 0; g < 16; ++g) s += red2[g * RED_PITCH + tid];
      const float sc = bias[k] + s;
      if (sc > bestsc) { bestsc = sc; bestk = k; }
    }
  }

  if (tid < 64) {
    const size_t o = ((size_t)kh * NPTS + n0 + tid) * 2;
    part[o] = bestsc;
    part[o + 1] = __int_as_float(bestk);
  }
}

__global__ __launch_bounds__(256) void gmm_merge(
    const float* __restrict__ part, int* __restrict__ out)
{
  const int n = blockIdx.x * 256 + threadIdx.x;
  const float s0 = part[(size_t)n * 2];
  const int k0 = __float_as_int(part[(size_t)n * 2 + 1]);
  const float s1 = part[((size_t)NPTS + n) * 2];
  const int k1 = __float_as_int(part[((size_t)NPTS + n) * 2 + 1]);
  out[n] = (s1 > s0) ? k1 : k0;
}

extern "C" void kernel_launch(void* const* d_in, const int* in_sizes, int n_in,
                              void* d_out, int out_size, void* d_ws, size_t ws_size,
                              hipStream_t stream)
{
  const float* x   = (const float*)d_in[0];   // (8192, 256)
  const float* mu  = (const float*)d_in[1];   // (64, 256)
  const float* var = (const float*)d_in[2];   // (64, 256, 256)
  const float* pi  = (const float*)d_in[3];   // (64,)

  char* ws = (char*)d_ws;
  float* Gt   = (float*)ws;                                   // K*D*D floats
  float* tvec = (float*)(ws + (size_t)KC * D * D * sizeof(float));
  float* bias = tvec + (size_t)KC * D;
  float* part = bias + KC;                                    // 2*N*2 floats
  int* out = (int*)d_out;

  gmm_preproc<<<KC, 256, 0, stream>>>(var, mu, pi, Gt, tvec, bias);
  gmm_score<<<256, 256, 0, stream>>>(x, Gt, tvec, bias, part);
  gmm_merge<<<NPTS / 256, 256, 0, stream>>>(part, out);
}

// Round 7
// 1383.841 us; speedup vs baseline: 2.4819x; 1.2639x over previous
//
#include <hip/hip_runtime.h>
#include <math.h>

#define D 256
#define KC 64
#define NPTS 8192
#define TRI ((D*(D+1))/2)

#define WSZ 33024             // odd-padded packed triangle size (floats)
#define FR_PER_CL 72          // triangular 16x16x32 fragments per cluster
#define SH_PER_CL (FR_PER_CL*512)           // shorts per cluster per plane
#define PLANE_SH ((size_t)KC*SH_PER_CL)     // shorts per plane

typedef __attribute__((ext_vector_type(8))) short short8;
typedef __attribute__((ext_vector_type(4))) float f32x4;

__device__ __forceinline__ int wb(int r) { return (r*(r+1))/2 + (r>>1); }  // odd-padded row base
__device__ __forceinline__ unsigned short f2bf(float f) {                   // RNE float->bf16 bits
  unsigned u = __float_as_uint(f);
  u = (u + 0x7fffu + ((u >> 16) & 1u)) >> 16;
  return (unsigned short)u;
}
__device__ __forceinline__ float bf2f(unsigned short s) { return __uint_as_float(((unsigned)s) << 16); }
// fragment offset table: off[I] = cumsum of kcnt(I')=(I'+2)>>1 ; closed form
__device__ __forceinline__ int frag_off(int I) { int a = I >> 1; return (I & 1) ? (a+1)*(a+1) : a*(a+1); }

// ---------------------------------------------------------------------------
// Per-cluster preprocessing (register-resident blocked Cholesky + inversion,
// unchanged math from round 3). New output encoding: G emitted as THREE
// bf16 planes (hi, lo, r2 with hi+lo+r2 ~= fp32 exact) in triangular
// 16x16x32 MFMA B-fragment layout: plane[k][frag(I,kc)][l][j] where the
// element is G[p][i]^T = Gt[p][i], p = kc*32+(l>>4)*8+j, i = 16*I+(l&15).
// ---------------------------------------------------------------------------
__global__ __launch_bounds__(256, 1) void gmm_preproc(
    const float* __restrict__ var, const float* __restrict__ mu,
    const float* __restrict__ pi,
    unsigned short* __restrict__ planes, float* __restrict__ tvec,
    float* __restrict__ bias)
{
  __shared__ float W[WSZ];        // packed lower triangle, odd-padded rows
  __shared__ float Tbuf[64*65];   // phase1: dense zero-padded U; phase2: T scratch
  __shared__ float colbuf[D];
  __shared__ float red[256];

  const int k = blockIdx.x, tid = threadIdx.x;
  const int lane = tid & 63, wid = tid >> 6;
  const float* A = var + (size_t)k*D*D;

  // ---- load packed lower triangle ----
  for (int idx = tid; idx < TRI; idx += 256) {
    int i = (int)((sqrtf(8.0f*(float)idx + 1.0f) - 1.0f)*0.5f);
    while ((i+1)*(i+2)/2 <= idx) ++i;
    while (i*(i+1)/2 > idx) --i;
    const int p = idx - i*(i+1)/2;
    W[wb(i) + p] = A[i*D + p];
  }
  __syncthreads();

  // ---- phase 1: blocked Cholesky, register-resident diag core ----
#pragma unroll 1
  for (int jb = 0; jb < 4; ++jb) {
    const int c0 = jb*64, c1 = c0 + 64, m = 256 - c1;

    if (wid == 0) {
      const int rbase = wb(c0 + lane) + c0;
      float Lrow[64];
#pragma unroll
      for (int p = 0; p < 64; ++p) Lrow[p] = W[rbase + p];

      float mydinv = 0.0f;
#pragma unroll
      for (int j = 0; j < 64; ++j) {
        const float dj = sqrtf(__shfl(Lrow[j], j, 64));
        const float dinv = 1.0f / dj;
        const float c = Lrow[j] * dinv;
        Lrow[j] = (lane == j) ? dj : c;
        mydinv = (lane == j) ? dinv : mydinv;
#pragma unroll
        for (int p = j + 1; p < 64; ++p) {
          const float cp = __shfl(c, p, 64);
          Lrow[p] -= c * cp;
        }
      }

      float Grow[64];
#pragma unroll
      for (int j = 0; j < 64; ++j) Grow[j] = 0.0f;
#pragma unroll
      for (int p = 0; p < 64; ++p) {
#pragma unroll
        for (int j = 0; j <= p; ++j) {
          const float fin = (((j == p) ? 1.0f : 0.0f) - Grow[j]) * mydinv;
          Grow[j] = (lane == p) ? fin : Grow[j];
        }
        const float lp = (lane > p) ? Lrow[p] : 0.0f;
#pragma unroll
        for (int j = 0; j <= p; ++j) {
          const float gpj = __shfl(Grow[j], p, 64);
          Grow[j] += lp * gpj;
        }
      }

#pragma unroll
      for (int j = 0; j < 64; ++j) {
        if (j <= lane) W[rbase + j] = Grow[j];
        Tbuf[lane*65 + j] = (j <= lane) ? Grow[j] : 0.0f;
      }
    }
    __syncthreads();

    // TRSM: L21 = A21 * U^T via uniform LDS broadcasts
    if (tid < m) {
      const int rb = wb(c1 + tid) + c0;
      float row[64];
#pragma unroll
      for (int p = 0; p < 64; ++p) row[p] = W[rb + p];
      for (int j = 0; j < 64; ++j) {
        const float* up = &Tbuf[j*65];
        float a0 = 0.f, a1 = 0.f, a2 = 0.f, a3 = 0.f;
#pragma unroll
        for (int p = 0; p < 64; p += 4) {
          a0 += row[p]   * up[p];
          a1 += row[p+1] * up[p+1];
          a2 += row[p+2] * up[p+2];
          a3 += row[p+3] * up[p+3];
        }
        W[rb + j] = (a0 + a1) + (a2 + a3);
      }
    }
    __syncthreads();

    // SYRK: trailing triangle -= L21 * L21^T
    if (m > 0) {
      const int nt = m >> 2, ntri = nt*(nt+1)/2;
      for (int tau = tid; tau < ntri; tau += 256) {
        int ti = (int)((sqrtf(8.0f*(float)tau + 1.0f) - 1.0f)*0.5f);
        while ((ti+1)*(ti+2)/2 <= tau) ++ti;
        while (ti*(ti+1)/2 > tau) --ti;
        const int tl = tau - ti*(ti+1)/2;
        const int i0 = c1 + ti*4, l0 = c1 + tl*4;
        const int ib[4] = {wb(i0), wb(i0+1), wb(i0+2), wb(i0+3)};
        const int lb[4] = {wb(l0), wb(l0+1), wb(l0+2), wb(l0+3)};
        float acc[4][4];
#pragma unroll
        for (int a = 0; a < 4; ++a)
#pragma unroll
          for (int b = 0; b < 4; ++b) acc[a][b] = 0.0f;
        for (int p = 0; p < 64; ++p) {
          const int cp = c0 + p;
          float av[4], bv[4];
#pragma unroll
          for (int a = 0; a < 4; ++a) av[a] = W[ib[a] + cp];
#pragma unroll
          for (int b = 0; b < 4; ++b) bv[b] = W[lb[b] + cp];
#pragma unroll
          for (int a = 0; a < 4; ++a)
#pragma unroll
            for (int b = 0; b < 4; ++b) acc[a][b] += av[a]*bv[b];
        }
#pragma unroll
        for (int a = 0; a < 4; ++a)
#pragma unroll
          for (int b = 0; b < 4; ++b) {
            const int rr = i0 + a, cc = l0 + b;
            if (cc <= rr) W[ib[a] + cc] -= acc[a][b];
          }
      }
    }
    __syncthreads();
  }

  // ---- phase 2: blocked in-place inversion G = L^{-1} ----
  const int ti2 = tid >> 4, tj2 = tid & 15;
  const int i0g = ti2*4, j0g = tj2*4;
#pragma unroll 1
  for (int J = 0; J < 3; ++J) {
#pragma unroll 1
    for (int I = J + 1; I < 4; ++I) {
      float acc[4][4];
#pragma unroll
      for (int q = 0; q < 4; ++q)
#pragma unroll
        for (int r = 0; r < 4; ++r) acc[q][r] = 0.0f;
      for (int K = J; K < I; ++K) {
        const int arow = 64*I, brow = 64*K;
        const bool dK = (K == J);
        for (int p = 0; p < 64; ++p) {
          float av[4], bv[4];
#pragma unroll
          for (int q = 0; q < 4; ++q) av[q] = W[wb(arow + i0g + q) + 64*K + p];
#pragma unroll
          for (int r = 0; r < 4; ++r) {
            const float raw = W[wb(brow + p) + 64*J + j0g + r];
            bv[r] = (dK && (j0g + r > p)) ? 0.0f : raw;
          }
#pragma unroll
          for (int q = 0; q < 4; ++q)
#pragma unroll
            for (int r = 0; r < 4; ++r) acc[q][r] += av[q]*bv[r];
        }
      }
#pragma unroll
      for (int q = 0; q < 4; ++q)
#pragma unroll
        for (int r = 0; r < 4; ++r) Tbuf[(i0g+q)*65 + j0g + r] = acc[q][r];
      __syncthreads();

      float g[4][4];
#pragma unroll
      for (int q = 0; q < 4; ++q)
#pragma unroll
        for (int r = 0; r < 4; ++r) g[q][r] = 0.0f;
      for (int p = 0; p < 64; ++p) {
        float uv[4], tv4[4];
#pragma unroll
        for (int q = 0; q < 4; ++q) {
          const int ir = i0g + q;
          uv[q] = (p <= ir) ? W[wb(64*I + ir) + 64*I + p] : 0.0f;
        }
#pragma unroll
        for (int r = 0; r < 4; ++r) tv4[r] = Tbuf[p*65 + j0g + r];
#pragma unroll
        for (int q = 0; q < 4; ++q)
#pragma unroll
          for (int r = 0; r < 4; ++r) g[q][r] += uv[q]*tv4[r];
      }
      __syncthreads();
#pragma unroll
      for (int q = 0; q < 4; ++q)
#pragma unroll
        for (int r = 0; r < 4; ++r)
          W[wb(64*I + i0g + q) + 64*J + j0g + r] = -g[q][r];
      __syncthreads();
    }
  }

  // ---- phase 3: t = G*mu, bias ----
  colbuf[tid] = mu[k*D + tid];
  __syncthreads();
  {
    const int rb4 = wb(tid);
    float s = 0.0f;
    for (int p = 0; p <= tid; ++p) s += W[rb4 + p]*colbuf[p];
    tvec[k*D + tid] = s;
    red[tid] = s*s;
  }
  __syncthreads();
  for (int st = 128; st > 0; st >>= 1) { if (tid < st) red[tid] += red[tid+st]; __syncthreads(); }
  const float t2 = red[0];
  __syncthreads();
  red[tid] = logf(W[wb(tid) + tid]);
  __syncthreads();
  for (int st = 128; st > 0; st >>= 1) { if (tid < st) red[tid] += red[tid+st]; __syncthreads(); }
  if (tid == 0) bias[k] = logf(pi[k]) + red[0] - 0.5f*t2;
  __syncthreads();

  // ---- pack 3 bf16 planes in MFMA B-fragment triangular layout ----
  for (int e = tid; e < SH_PER_CL; e += 256) {
    const int f = e >> 9, wrd = e & 511, l = wrd >> 3, j = wrd & 7;
    const int I = (f>=1)+(f>=2)+(f>=4)+(f>=6)+(f>=9)+(f>=12)+(f>=16)+(f>=20)
                +(f>=25)+(f>=30)+(f>=36)+(f>=42)+(f>=49)+(f>=56)+(f>=64);
    const int kc = f - frag_off(I);
    const int li = l & 15, hh = l >> 4;
    const int p = kc*32 + hh*8 + j, i2 = I*16 + li;
    const float g = (p <= i2) ? W[wb(i2) + p] : 0.0f;   // Gt[p][i] = G[i][p]
    const unsigned short hb = f2bf(g); const float hf = bf2f(hb);
    const float r1 = g - hf;
    const unsigned short lb = f2bf(r1); const float lf = bf2f(lb);
    const unsigned short rb = f2bf(r1 - lf);
    const size_t base = (size_t)k*SH_PER_CL + e;
    planes[base] = hb;
    planes[PLANE_SH + base] = lb;
    planes[2*PLANE_SH + base] = rb;
  }
}

// ---------------------------------------------------------------------------
// MFMA scoring: grid 512 = 64 n-tiles(128 pts) x 8 cluster-octants.
// Per wave: 32 rows (2 MFMA row-subtiles), A-frags (x hi/lo) in registers,
// B-frags streamed from global bf16 planes (L2/L3-resident). Split-2:
// hh + lh + hl products. No LDS. Writes per-octant best/bestk/second.
// ---------------------------------------------------------------------------
__global__ __launch_bounds__(256, 2) void gmm_score_mfma(
    const float* __restrict__ x, const unsigned short* __restrict__ planes,
    const float* __restrict__ tvec, const float* __restrict__ bias,
    float* __restrict__ partq)
{
  const int tid = threadIdx.x, lane = tid & 63, w = tid >> 6;
  const int li = lane & 15, h = lane >> 4;
  const int ntile = blockIdx.x & 63, kq = blockIdx.x >> 6;
  const int n0 = ntile*128 + w*32;

  short8 ah[2][8], al[2][8];
#pragma unroll
  for (int s = 0; s < 2; ++s) {
    const float* xr = x + (size_t)(n0 + s*16 + li)*D;
#pragma unroll
    for (int kc = 0; kc < 8; ++kc) {
      const float4 v0 = *reinterpret_cast<const float4*>(xr + kc*32 + h*8);
      const float4 v1 = *reinterpret_cast<const float4*>(xr + kc*32 + h*8 + 4);
      const float xv[8] = {v0.x, v0.y, v0.z, v0.w, v1.x, v1.y, v1.z, v1.w};
#pragma unroll
      for (int j = 0; j < 8; ++j) {
        const unsigned short hb = f2bf(xv[j]);
        ah[s][kc][j] = (short)hb;
        al[s][kc][j] = (short)f2bf(xv[j] - bf2f(hb));
      }
    }
  }

  float best0[4], sec0[4], best1[4], sec1[4];
  int bk0[4], bk1[4];
#pragma unroll
  for (int j = 0; j < 4; ++j) {
    best0[j] = -3.0e38f; sec0[j] = -3.0e38f; bk0[j] = 0;
    best1[j] = -3.0e38f; sec1[j] = -3.0e38f; bk1[j] = 0;
  }

#pragma unroll 1
  for (int kk = 0; kk < 8; ++kk) {
    const int k = kq*8 + kk;
    const unsigned short* bhB = planes + (size_t)k*SH_PER_CL;
    const unsigned short* blB = bhB + PLANE_SH;
    const float* tk = tvec + k*D;
    float p0[4] = {0.f,0.f,0.f,0.f}, p1[4] = {0.f,0.f,0.f,0.f};
#pragma unroll
    for (int I = 0; I < 16; ++I) {
      const int fb = frag_off(I);
      const int kcnt = (I + 2) >> 1;
      f32x4 acc0 = {0.f,0.f,0.f,0.f}, acc1 = {0.f,0.f,0.f,0.f};
#pragma unroll
      for (int kc = 0; kc < kcnt; ++kc) {
        const int fo = (fb + kc)*512 + lane*8;
        const short8 bh = *reinterpret_cast<const short8*>(bhB + fo);
        const short8 bl = *reinterpret_cast<const short8*>(blB + fo);
        acc0 = __builtin_amdgcn_mfma_f32_16x16x32_bf16(ah[0][kc], bh, acc0, 0, 0, 0);
        acc1 = __builtin_amdgcn_mfma_f32_16x16x32_bf16(ah[1][kc], bh, acc1, 0, 0, 0);
        acc0 = __builtin_amdgcn_mfma_f32_16x16x32_bf16(al[0][kc], bh, acc0, 0, 0, 0);
        acc1 = __builtin_amdgcn_mfma_f32_16x16x32_bf16(al[1][kc], bh, acc1, 0, 0, 0);
        acc0 = __builtin_amdgcn_mfma_f32_16x16x32_bf16(ah[0][kc], bl, acc0, 0, 0, 0);
        acc1 = __builtin_amdgcn_mfma_f32_16x16x32_bf16(ah[1][kc], bl, acc1, 0, 0, 0);
      }
      const float t = tk[I*16 + li];
#pragma unroll
      for (int j = 0; j < 4; ++j) {
        float y = acc0[j]; p0[j] += y*(t - 0.5f*y);
        y = acc1[j];       p1[j] += y*(t - 0.5f*y);
      }
    }
#pragma unroll
    for (int mloc = 1; mloc < 16; mloc <<= 1) {
#pragma unroll
      for (int j = 0; j < 4; ++j) {
        p0[j] += __shfl_xor(p0[j], mloc, 64);
        p1[j] += __shfl_xor(p1[j], mloc, 64);
      }
    }
    const float bs = bias[k];
#pragma unroll
    for (int j = 0; j < 4; ++j) {
      const float s0v = bs + p0[j];
      if (s0v > best0[j]) { sec0[j] = best0[j]; best0[j] = s0v; bk0[j] = k; }
      else if (s0v > sec0[j]) sec0[j] = s0v;
      const float s1v = bs + p1[j];
      if (s1v > best1[j]) { sec1[j] = best1[j]; best1[j] = s1v; bk1[j] = k; }
      else if (s1v > sec1[j]) sec1[j] = s1v;
    }
  }

  if (li == 0) {
#pragma unroll
    for (int j = 0; j < 4; ++j) {
      const size_t r0 = ((size_t)kq*NPTS + n0 + h*4 + j)*3;
      partq[r0] = best0[j]; partq[r0+1] = __int_as_float(bk0[j]); partq[r0+2] = sec0[j];
      const size_t r1 = ((size_t)kq*NPTS + n0 + 16 + h*4 + j)*3;
      partq[r1] = best1[j]; partq[r1+1] = __int_as_float(bk1[j]); partq[r1+2] = sec1[j];
    }
  }
}

// ---------------------------------------------------------------------------
// Merge 8 octants; flag small-margin points for exact re-scoring.
// ---------------------------------------------------------------------------
__global__ __launch_bounds__(256) void gmm_merge(
    const float* __restrict__ partq, int* __restrict__ out,
    int* __restrict__ flaglist, int* __restrict__ flagcnt)
{
  const int n = blockIdx.x*256 + threadIdx.x;
  float b = -3.0e38f, s2 = -3.0e38f; int bk = 0;
#pragma unroll
  for (int q = 0; q < 8; ++q) {
    const size_t o = ((size_t)q*NPTS + n)*3;
    const float bq = partq[o];
    const int kq_ = __float_as_int(partq[o+1]);
    const float sq = partq[o+2];
    if (bq > b) { s2 = fmaxf(b, sq); b = bq; bk = kq_; }
    else        { s2 = fmaxf(s2, bq); }
  }
  out[n] = bk;
  if (b - s2 < 0.25f) {
    const int idx = atomicAdd(flagcnt, 1);
    flaglist[idx] = n;
  }
}

// ---------------------------------------------------------------------------
// Exact (fp32-grade, split-3 x split-3 truncated at level 2 => ~2^-24) re-score
// of flagged points over all 64 clusters. Block = 16 points; wave w covers
// clusters [16w,16w+16); 4-way LDS merge with ascending-k tie preference.
// ---------------------------------------------------------------------------
__global__ __launch_bounds__(256) void gmm_exact(
    const float* __restrict__ x, const unsigned short* __restrict__ planes,
    const float* __restrict__ tvec, const float* __restrict__ bias,
    const int* __restrict__ flaglist, const int* __restrict__ flagcnt,
    int* __restrict__ out)
{
  __shared__ float lbest[4][16];
  __shared__ int   lbk[4][16];
  const int tid = threadIdx.x, lane = tid & 63, w = tid >> 6;
  const int li = lane & 15, h = lane >> 4;
  const int cnt = *flagcnt;

#pragma unroll 1
  for (int sb = blockIdx.x*16; sb < cnt; sb += gridDim.x*16) {
    const int slot = sb + li;
    const int row = (slot < cnt) ? flaglist[slot] : 0;

    short8 ah[8], al[8], ar[8];
    const float* xr = x + (size_t)row*D;
#pragma unroll
    for (int kc = 0; kc < 8; ++kc) {
      const float4 v0 = *reinterpret_cast<const float4*>(xr + kc*32 + h*8);
      const float4 v1 = *reinterpret_cast<const float4*>(xr + kc*32 + h*8 + 4);
      const float xv[8] = {v0.x, v0.y, v0.z, v0.w, v1.x, v1.y, v1.z, v1.w};
#pragma unroll
      for (int j = 0; j < 8; ++j) {
        const unsigned short hb = f2bf(xv[j]); const float hf = bf2f(hb);
        const float r1 = xv[j] - hf;
        const unsigned short lb = f2bf(r1); const float lf = bf2f(lb);
        ah[kc][j] = (short)hb; al[kc][j] = (short)lb; ar[kc][j] = (short)f2bf(r1 - lf);
      }
    }

    float best[4]; int bk[4];
#pragma unroll
    for (int j = 0; j < 4; ++j) { best[j] = -3.0e38f; bk[j] = 0; }

#pragma unroll 1
    for (int kk = 0; kk < 16; ++kk) {
      const int k = w*16 + kk;
      const unsigned short* bhB = planes + (size_t)k*SH_PER_CL;
      const unsigned short* blB = bhB + PLANE_SH;
      const unsigned short* brB = bhB + 2*PLANE_SH;
      const float* tk = tvec + k*D;
      float part[4] = {0.f,0.f,0.f,0.f};
#pragma unroll
      for (int I = 0; I < 16; ++I) {
        const int fb = frag_off(I);
        const int kcnt = (I + 2) >> 1;
        f32x4 a0 = {0.f,0.f,0.f,0.f}, a1 = {0.f,0.f,0.f,0.f}, a2 = {0.f,0.f,0.f,0.f};
#pragma unroll
        for (int kc = 0; kc < kcnt; ++kc) {
          const int fo = (fb + kc)*512 + lane*8;
          const short8 bh = *reinterpret_cast<const short8*>(bhB + fo);
          const short8 bl = *reinterpret_cast<const short8*>(blB + fo);
          const short8 br = *reinterpret_cast<const short8*>(brB + fo);
          a0 = __builtin_amdgcn_mfma_f32_16x16x32_bf16(ah[kc], bh, a0, 0, 0, 0);
          a0 = __builtin_amdgcn_mfma_f32_16x16x32_bf16(al[kc], bh, a0, 0, 0, 0);
          a0 = __builtin_amdgcn_mfma_f32_16x16x32_bf16(ar[kc], bh, a0, 0, 0, 0);
          a1 = __builtin_amdgcn_mfma_f32_16x16x32_bf16(ah[kc], bl, a1, 0, 0, 0);
          a1 = __builtin_amdgcn_mfma_f32_16x16x32_bf16(al[kc], bl, a1, 0, 0, 0);
          a2 = __builtin_amdgcn_mfma_f32_16x16x32_bf16(ah[kc], br, a2, 0, 0, 0);
        }
        const float t = tk[I*16 + li];
#pragma unroll
        for (int j = 0; j < 4; ++j) {
          const float y = a0[j] + a1[j] + a2[j];
          part[j] += y*(t - 0.5f*y);
        }
      }
#pragma unroll
      for (int mloc = 1; mloc < 16; mloc <<= 1) {
#pragma unroll
        for (int j = 0; j < 4; ++j) part[j] += __shfl_xor(part[j], mloc, 64);
      }
      const float bs = bias[k];
#pragma unroll
      for (int j = 0; j < 4; ++j) {
        const float sc = bs + part[j];
        if (sc > best[j]) { best[j] = sc; bk[j] = k; }
      }
    }

    if (li == 0) {
#pragma unroll
      for (int j = 0; j < 4; ++j) { lbest[w][h*4+j] = best[j]; lbk[w][h*4+j] = bk[j]; }
    }
    __syncthreads();
    if (tid < 16 && (sb + tid) < cnt) {
      float b = lbest[0][tid]; int k_ = lbk[0][tid];
#pragma unroll
      for (int ww = 1; ww < 4; ++ww)
        if (lbest[ww][tid] > b) { b = lbest[ww][tid]; k_ = lbk[ww][tid]; }
      out[flaglist[sb + tid]] = k_;
    }
    __syncthreads();
  }
}

extern "C" void kernel_launch(void* const* d_in, const int* in_sizes, int n_in,
                              void* d_out, int out_size, void* d_ws, size_t ws_size,
                              hipStream_t stream)
{
  const float* x   = (const float*)d_in[0];   // (8192, 256)
  const float* mu  = (const float*)d_in[1];   // (64, 256)
  const float* var = (const float*)d_in[2];   // (64, 256, 256)
  const float* pi  = (const float*)d_in[3];   // (64,)

  char* ws = (char*)d_ws;
  unsigned short* planes = (unsigned short*)ws;                      // 3 planes, 14.16 MB
  float* tvec = (float*)(ws + 3*PLANE_SH*sizeof(unsigned short));    // 64 KB
  float* bias = tvec + KC*D;                                         // 64 floats (pad to 256)
  float* partq = bias + 256;                                         // 8*8192*3 floats
  int* flaglist = (int*)(partq + (size_t)8*NPTS*3);                  // 8192 ints
  int* flagcnt = flaglist + NPTS;
  int* out = (int*)d_out;

  gmm_preproc<<<KC, 256, 0, stream>>>(var, mu, pi, planes, tvec, bias);
  gmm_score_mfma<<<512, 256, 0, stream>>>(x, planes, tvec, bias, partq);
  hipMemsetAsync(flagcnt, 0, sizeof(int), stream);
  gmm_merge<<<NPTS/256, 256, 0, stream>>>(partq, out, flaglist, flagcnt);
  gmm_exact<<<64, 256, 0, stream>>>(x, planes, tvec, bias, flaglist, flagcnt, out);
}

// Round 8
// 1235.808 us; speedup vs baseline: 2.7792x; 1.1198x over previous
//
#include <hip/hip_runtime.h>
#include <math.h>

#define D 256
#define KC 64
#define NPTS 8192
#define TRI ((D*(D+1))/2)

#define WSZ 33024             // odd-padded packed triangle size (floats)
#define FR_PER_CL 72          // triangular 16x16x32 fragments per cluster
#define SH_PER_CL (FR_PER_CL*512)           // shorts per cluster per plane
#define PLANE_SH ((size_t)KC*SH_PER_CL)     // shorts per plane

typedef __attribute__((ext_vector_type(8))) short short8;
typedef __attribute__((ext_vector_type(4))) float f32x4;

__device__ __forceinline__ int wb(int r) { return (r*(r+1))/2 + (r>>1); }  // odd-padded row base
__device__ __forceinline__ unsigned short f2bf(float f) {                   // RNE float->bf16 bits
  unsigned u = __float_as_uint(f);
  u = (u + 0x7fffu + ((u >> 16) & 1u)) >> 16;
  return (unsigned short)u;
}
__device__ __forceinline__ float bf2f(unsigned short s) { return __uint_as_float(((unsigned)s) << 16); }
// fragment offset table: off[I] = cumsum of kcnt(I')=(I'+2)>>1 ; closed form
__device__ __forceinline__ int frag_off(int I) { int a = I >> 1; return (I & 1) ? (a+1)*(a+1) : a*(a+1); }

// ---------------------------------------------------------------------------
// Per-cluster preprocessing. Diag core now uses a SINGLE 64-register array:
// Cholesky factors in place, then forward-substitution aliases G over L
// (L[p] is dead after step p reads it) -- ~70 live VGPRs, no scratch spill.
// ---------------------------------------------------------------------------
__global__ __launch_bounds__(256, 1) void gmm_preproc(
    const float* __restrict__ var, const float* __restrict__ mu,
    const float* __restrict__ pi,
    unsigned short* __restrict__ planes, float* __restrict__ tvec,
    float* __restrict__ bias)
{
  __shared__ float W[WSZ];        // packed lower triangle, odd-padded rows
  __shared__ float Tbuf[64*65];   // phase1: dense zero-padded U; phase2: T scratch
  __shared__ float colbuf[D];
  __shared__ float red[256];

  const int k = blockIdx.x, tid = threadIdx.x;
  const int lane = tid & 63, wid = tid >> 6;
  const float* A = var + (size_t)k*D*D;

  // ---- load packed lower triangle ----
  for (int idx = tid; idx < TRI; idx += 256) {
    int i = (int)((sqrtf(8.0f*(float)idx + 1.0f) - 1.0f)*0.5f);
    while ((i+1)*(i+2)/2 <= idx) ++i;
    while (i*(i+1)/2 > idx) --i;
    const int p = idx - i*(i+1)/2;
    W[wb(i) + p] = A[i*D + p];
  }
  __syncthreads();

  // ---- phase 1: blocked Cholesky, single-array register diag core ----
#pragma unroll 1
  for (int jb = 0; jb < 4; ++jb) {
    const int c0 = jb*64, c1 = c0 + 64, m = 256 - c1;

    if (wid == 0) {
      const int rbase = wb(c0 + lane) + c0;
      float Arow[64];
#pragma unroll
      for (int p = 0; p < 64; ++p) Arow[p] = W[rbase + p];   // p>lane: garbage, never escapes

      // in-register Cholesky (row per lane)
      float mydinv = 0.0f;
#pragma unroll
      for (int j = 0; j < 64; ++j) {
        const float dj = sqrtf(__shfl(Arow[j], j, 64));
        const float dinv = 1.0f / dj;
        const float c = Arow[j] * dinv;           // valid for lane > j
        Arow[j] = (lane == j) ? dj : c;
        mydinv = (lane == j) ? dinv : mydinv;
#pragma unroll
        for (int p = j + 1; p < 64; ++p) {
          const float cp = __shfl(c, p, 64);      // lane p's c (readlane)
          Arow[p] -= c * cp;                      // i==p updates diagonal; i<p garbage
        }
      }

      // G11 = inv(L11), forward substitution FUSED over the same array.
      // At step p: lp=A[p] (L[i][p], then dead), finalize lane p in place,
      // accumulate A[j] += lp*G[p][j] (j<p), and ASSIGN A[p] = lp*G[p][p]
      // for lanes>p (clears L-residue; starts the j=p accumulator).
#pragma unroll
      for (int p = 0; p < 64; ++p) {
        const float lp = (lane > p) ? Arow[p] : 0.0f;
#pragma unroll
        for (int j = 0; j < p; ++j) {
          const float fin = (0.0f - Arow[j]) * mydinv;
          Arow[j] = (lane == p) ? fin : Arow[j];
        }
        Arow[p] = (lane == p) ? mydinv : Arow[p];
#pragma unroll
        for (int j = 0; j < p; ++j) {
          const float gpj = __shfl(Arow[j], p, 64);   // lane p's finalized G[p][j]
          Arow[j] += lp * gpj;
        }
        const float gpp = __shfl(Arow[p], p, 64);     // = lane p's mydinv
        Arow[p] = (lane > p) ? (lp * gpp) : Arow[p];
      }

      // publish G11: packed W diag block (j<=lane) + dense zero-padded Tbuf
#pragma unroll
      for (int j = 0; j < 64; ++j) {
        if (j <= lane) W[rbase + j] = Arow[j];
        Tbuf[lane*65 + j] = (j <= lane) ? Arow[j] : 0.0f;
      }
    }
    __syncthreads();

    // TRSM: L21 = A21 * U^T via uniform LDS broadcasts
    if (tid < m) {
      const int rb = wb(c1 + tid) + c0;
      float row[64];
#pragma unroll
      for (int p = 0; p < 64; ++p) row[p] = W[rb + p];
      for (int j = 0; j < 64; ++j) {
        const float* up = &Tbuf[j*65];
        float a0 = 0.f, a1 = 0.f, a2 = 0.f, a3 = 0.f;
#pragma unroll
        for (int p = 0; p < 64; p += 4) {
          a0 += row[p]   * up[p];
          a1 += row[p+1] * up[p+1];
          a2 += row[p+2] * up[p+2];
          a3 += row[p+3] * up[p+3];
        }
        W[rb + j] = (a0 + a1) + (a2 + a3);
      }
    }
    __syncthreads();

    // SYRK: trailing triangle -= L21 * L21^T
    if (m > 0) {
      const int nt = m >> 2, ntri = nt*(nt+1)/2;
      for (int tau = tid; tau < ntri; tau += 256) {
        int ti = (int)((sqrtf(8.0f*(float)tau + 1.0f) - 1.0f)*0.5f);
        while ((ti+1)*(ti+2)/2 <= tau) ++ti;
        while (ti*(ti+1)/2 > tau) --ti;
        const int tl = tau - ti*(ti+1)/2;
        const int i0 = c1 + ti*4, l0 = c1 + tl*4;
        const int ib[4] = {wb(i0), wb(i0+1), wb(i0+2), wb(i0+3)};
        const int lb[4] = {wb(l0), wb(l0+1), wb(l0+2), wb(l0+3)};
        float acc[4][4];
#pragma unroll
        for (int a = 0; a < 4; ++a)
#pragma unroll
          for (int b = 0; b < 4; ++b) acc[a][b] = 0.0f;
        for (int p = 0; p < 64; ++p) {
          const int cp = c0 + p;
          float av[4], bv[4];
#pragma unroll
          for (int a = 0; a < 4; ++a) av[a] = W[ib[a] + cp];
#pragma unroll
          for (int b = 0; b < 4; ++b) bv[b] = W[lb[b] + cp];
#pragma unroll
          for (int a = 0; a < 4; ++a)
#pragma unroll
            for (int b = 0; b < 4; ++b) acc[a][b] += av[a]*bv[b];
        }
#pragma unroll
        for (int a = 0; a < 4; ++a)
#pragma unroll
          for (int b = 0; b < 4; ++b) {
            const int rr = i0 + a, cc = l0 + b;
            if (cc <= rr) W[ib[a] + cc] -= acc[a][b];
          }
      }
    }
    __syncthreads();
  }

  // ---- phase 2: blocked in-place inversion G = L^{-1} ----
  const int ti2 = tid >> 4, tj2 = tid & 15;
  const int i0g = ti2*4, j0g = tj2*4;
#pragma unroll 1
  for (int J = 0; J < 3; ++J) {
#pragma unroll 1
    for (int I = J + 1; I < 4; ++I) {
      float acc[4][4];
#pragma unroll
      for (int q = 0; q < 4; ++q)
#pragma unroll
        for (int r = 0; r < 4; ++r) acc[q][r] = 0.0f;
      for (int K = J; K < I; ++K) {
        const int arow = 64*I, brow = 64*K;
        const bool dK = (K == J);
        for (int p = 0; p < 64; ++p) {
          float av[4], bv[4];
#pragma unroll
          for (int q = 0; q < 4; ++q) av[q] = W[wb(arow + i0g + q) + 64*K + p];
#pragma unroll
          for (int r = 0; r < 4; ++r) {
            const float raw = W[wb(brow + p) + 64*J + j0g + r];
            bv[r] = (dK && (j0g + r > p)) ? 0.0f : raw;
          }
#pragma unroll
          for (int q = 0; q < 4; ++q)
#pragma unroll
            for (int r = 0; r < 4; ++r) acc[q][r] += av[q]*bv[r];
        }
      }
#pragma unroll
      for (int q = 0; q < 4; ++q)
#pragma unroll
        for (int r = 0; r < 4; ++r) Tbuf[(i0g+q)*65 + j0g + r] = acc[q][r];
      __syncthreads();

      float g[4][4];
#pragma unroll
      for (int q = 0; q < 4; ++q)
#pragma unroll
        for (int r = 0; r < 4; ++r) g[q][r] = 0.0f;
      for (int p = 0; p < 64; ++p) {
        float uv[4], tv4[4];
#pragma unroll
        for (int q = 0; q < 4; ++q) {
          const int ir = i0g + q;
          uv[q] = (p <= ir) ? W[wb(64*I + ir) + 64*I + p] : 0.0f;
        }
#pragma unroll
        for (int r = 0; r < 4; ++r) tv4[r] = Tbuf[p*65 + j0g + r];
#pragma unroll
        for (int q = 0; q < 4; ++q)
#pragma unroll
          for (int r = 0; r < 4; ++r) g[q][r] += uv[q]*tv4[r];
      }
      __syncthreads();
#pragma unroll
      for (int q = 0; q < 4; ++q)
#pragma unroll
        for (int r = 0; r < 4; ++r)
          W[wb(64*I + i0g + q) + 64*J + j0g + r] = -g[q][r];
      __syncthreads();
    }
  }

  // ---- phase 3: t = G*mu, bias ----
  colbuf[tid] = mu[k*D + tid];
  __syncthreads();
  {
    const int rb4 = wb(tid);
    float s = 0.0f;
    for (int p = 0; p <= tid; ++p) s += W[rb4 + p]*colbuf[p];
    tvec[k*D + tid] = s;
    red[tid] = s*s;
  }
  __syncthreads();
  for (int st = 128; st > 0; st >>= 1) { if (tid < st) red[tid] += red[tid+st]; __syncthreads(); }
  const float t2 = red[0];
  __syncthreads();
  red[tid] = logf(W[wb(tid) + tid]);
  __syncthreads();
  for (int st = 128; st > 0; st >>= 1) { if (tid < st) red[tid] += red[tid+st]; __syncthreads(); }
  if (tid == 0) bias[k] = logf(pi[k]) + red[0] - 0.5f*t2;
  __syncthreads();

  // ---- pack 3 bf16 planes in MFMA B-fragment triangular layout ----
  for (int e = tid; e < SH_PER_CL; e += 256) {
    const int f = e >> 9, wrd = e & 511, l = wrd >> 3, j = wrd & 7;
    const int I = (f>=1)+(f>=2)+(f>=4)+(f>=6)+(f>=9)+(f>=12)+(f>=16)+(f>=20)
                +(f>=25)+(f>=30)+(f>=36)+(f>=42)+(f>=49)+(f>=56)+(f>=64);
    const int kc = f - frag_off(I);
    const int li = l & 15, hh = l >> 4;
    const int p = kc*32 + hh*8 + j, i2 = I*16 + li;
    const float g = (p <= i2) ? W[wb(i2) + p] : 0.0f;   // Gt[p][i] = G[i][p]
    const unsigned short hb = f2bf(g); const float hf = bf2f(hb);
    const float r1 = g - hf;
    const unsigned short lb = f2bf(r1); const float lf = bf2f(lb);
    const unsigned short rb = f2bf(r1 - lf);
    const size_t base = (size_t)k*SH_PER_CL + e;
    planes[base] = hb;
    planes[PLANE_SH + base] = lb;
    planes[2*PLANE_SH + base] = rb;
  }
}

// ---------------------------------------------------------------------------
// MFMA scoring: grid 512 = 64 n-tiles(128 pts) x 8 cluster-octants.
// ---------------------------------------------------------------------------
__global__ __launch_bounds__(256, 2) void gmm_score_mfma(
    const float* __restrict__ x, const unsigned short* __restrict__ planes,
    const float* __restrict__ tvec, const float* __restrict__ bias,
    float* __restrict__ partq)
{
  const int tid = threadIdx.x, lane = tid & 63, w = tid >> 6;
  const int li = lane & 15, h = lane >> 4;
  const int ntile = blockIdx.x & 63, kq = blockIdx.x >> 6;
  const int n0 = ntile*128 + w*32;

  short8 ah[2][8], al[2][8];
#pragma unroll
  for (int s = 0; s < 2; ++s) {
    const float* xr = x + (size_t)(n0 + s*16 + li)*D;
#pragma unroll
    for (int kc = 0; kc < 8; ++kc) {
      const float4 v0 = *reinterpret_cast<const float4*>(xr + kc*32 + h*8);
      const float4 v1 = *reinterpret_cast<const float4*>(xr + kc*32 + h*8 + 4);
      const float xv[8] = {v0.x, v0.y, v0.z, v0.w, v1.x, v1.y, v1.z, v1.w};
#pragma unroll
      for (int j = 0; j < 8; ++j) {
        const unsigned short hb = f2bf(xv[j]);
        ah[s][kc][j] = (short)hb;
        al[s][kc][j] = (short)f2bf(xv[j] - bf2f(hb));
      }
    }
  }

  float best0[4], sec0[4], best1[4], sec1[4];
  int bk0[4], bk1[4];
#pragma unroll
  for (int j = 0; j < 4; ++j) {
    best0[j] = -3.0e38f; sec0[j] = -3.0e38f; bk0[j] = 0;
    best1[j] = -3.0e38f; sec1[j] = -3.0e38f; bk1[j] = 0;
  }

#pragma unroll 1
  for (int kk = 0; kk < 8; ++kk) {
    const int k = kq*8 + kk;
    const unsigned short* bhB = planes + (size_t)k*SH_PER_CL;
    const unsigned short* blB = bhB + PLANE_SH;
    const float* tk = tvec + k*D;
    float p0[4] = {0.f,0.f,0.f,0.f}, p1[4] = {0.f,0.f,0.f,0.f};
#pragma unroll
    for (int I = 0; I < 16; ++I) {
      const int fb = frag_off(I);
      const int kcnt = (I + 2) >> 1;
      f32x4 acc0 = {0.f,0.f,0.f,0.f}, acc1 = {0.f,0.f,0.f,0.f};
#pragma unroll
      for (int kc = 0; kc < kcnt; ++kc) {
        const int fo = (fb + kc)*512 + lane*8;
        const short8 bh = *reinterpret_cast<const short8*>(bhB + fo);
        const short8 bl = *reinterpret_cast<const short8*>(blB + fo);
        acc0 = __builtin_amdgcn_mfma_f32_16x16x32_bf16(ah[0][kc], bh, acc0, 0, 0, 0);
        acc1 = __builtin_amdgcn_mfma_f32_16x16x32_bf16(ah[1][kc], bh, acc1, 0, 0, 0);
        acc0 = __builtin_amdgcn_mfma_f32_16x16x32_bf16(al[0][kc], bh, acc0, 0, 0, 0);
        acc1 = __builtin_amdgcn_mfma_f32_16x16x32_bf16(al[1][kc], bh, acc1, 0, 0, 0);
        acc0 = __builtin_amdgcn_mfma_f32_16x16x32_bf16(ah[0][kc], bl, acc0, 0, 0, 0);
        acc1 = __builtin_amdgcn_mfma_f32_16x16x32_bf16(ah[1][kc], bl, acc1, 0, 0, 0);
      }
      const float t = tk[I*16 + li];
#pragma unroll
      for (int j = 0; j < 4; ++j) {
        float y = acc0[j]; p0[j] += y*(t - 0.5f*y);
        y = acc1[j];       p1[j] += y*(t - 0.5f*y);
      }
    }
#pragma unroll
    for (int mloc = 1; mloc < 16; mloc <<= 1) {
#pragma unroll
      for (int j = 0; j < 4; ++j) {
        p0[j] += __shfl_xor(p0[j], mloc, 64);
        p1[j] += __shfl_xor(p1[j], mloc, 64);
      }
    }
    const float bs = bias[k];
#pragma unroll
    for (int j = 0; j < 4; ++j) {
      const float s0v = bs + p0[j];
      if (s0v > best0[j]) { sec0[j] = best0[j]; best0[j] = s0v; bk0[j] = k; }
      else if (s0v > sec0[j]) sec0[j] = s0v;
      const float s1v = bs + p1[j];
      if (s1v > best1[j]) { sec1[j] = best1[j]; best1[j] = s1v; bk1[j] = k; }
      else if (s1v > sec1[j]) sec1[j] = s1v;
    }
  }

  if (li == 0) {
#pragma unroll
    for (int j = 0; j < 4; ++j) {
      const size_t r0 = ((size_t)kq*NPTS + n0 + h*4 + j)*3;
      partq[r0] = best0[j]; partq[r0+1] = __int_as_float(bk0[j]); partq[r0+2] = sec0[j];
      const size_t r1 = ((size_t)kq*NPTS + n0 + 16 + h*4 + j)*3;
      partq[r1] = best1[j]; partq[r1+1] = __int_as_float(bk1[j]); partq[r1+2] = sec1[j];
    }
  }
}

// ---------------------------------------------------------------------------
// Merge 8 octants; flag small-margin points for exact re-scoring.
// ---------------------------------------------------------------------------
__global__ __launch_bounds__(256) void gmm_merge(
    const float* __restrict__ partq, int* __restrict__ out,
    int* __restrict__ flaglist, int* __restrict__ flagcnt)
{
  const int n = blockIdx.x*256 + threadIdx.x;
  float b = -3.0e38f, s2 = -3.0e38f; int bk = 0;
#pragma unroll
  for (int q = 0; q < 8; ++q) {
    const size_t o = ((size_t)q*NPTS + n)*3;
    const float bq = partq[o];
    const int kq_ = __float_as_int(partq[o+1]);
    const float sq = partq[o+2];
    if (bq > b) { s2 = fmaxf(b, sq); b = bq; bk = kq_; }
    else        { s2 = fmaxf(s2, bq); }
  }
  out[n] = bk;
  if (b - s2 < 0.25f) {
    const int idx = atomicAdd(flagcnt, 1);
    flaglist[idx] = n;
  }
}

// ---------------------------------------------------------------------------
// Exact (split-3 x split-3 truncated, ~2^-24) re-score of flagged points.
// ---------------------------------------------------------------------------
__global__ __launch_bounds__(256) void gmm_exact(
    const float* __restrict__ x, const unsigned short* __restrict__ planes,
    const float* __restrict__ tvec, const float* __restrict__ bias,
    const int* __restrict__ flaglist, const int* __restrict__ flagcnt,
    int* __restrict__ out)
{
  __shared__ float lbest[4][16];
  __shared__ int   lbk[4][16];
  const int tid = threadIdx.x, lane = tid & 63, w = tid >> 6;
  const int li = lane & 15, h = lane >> 4;
  const int cnt = *flagcnt;

#pragma unroll 1
  for (int sb = blockIdx.x*16; sb < cnt; sb += gridDim.x*16) {
    const int slot = sb + li;
    const int row = (slot < cnt) ? flaglist[slot] : 0;

    short8 ah[8], al[8], ar[8];
    const float* xr = x + (size_t)row*D;
#pragma unroll
    for (int kc = 0; kc < 8; ++kc) {
      const float4 v0 = *reinterpret_cast<const float4*>(xr + kc*32 + h*8);
      const float4 v1 = *reinterpret_cast<const float4*>(xr + kc*32 + h*8 + 4);
      const float xv[8] = {v0.x, v0.y, v0.z, v0.w, v1.x, v1.y, v1.z, v1.w};
#pragma unroll
      for (int j = 0; j < 8; ++j) {
        const unsigned short hb = f2bf(xv[j]); const float hf = bf2f(hb);
        const float r1 = xv[j] - hf;
        const unsigned short lb = f2bf(r1); const float lf = bf2f(lb);
        ah[kc][j] = (short)hb; al[kc][j] = (short)lb; ar[kc][j] = (short)f2bf(r1 - lf);
      }
    }

    float best[4]; int bk[4];
#pragma unroll
    for (int j = 0; j < 4; ++j) { best[j] = -3.0e38f; bk[j] = 0; }

#pragma unroll 1
    for (int kk = 0; kk < 16; ++kk) {
      const int k = w*16 + kk;
      const unsigned short* bhB = planes + (size_t)k*SH_PER_CL;
      const unsigned short* blB = bhB + PLANE_SH;
      const unsigned short* brB = bhB + 2*PLANE_SH;
      const float* tk = tvec + k*D;
      float part[4] = {0.f,0.f,0.f,0.f};
#pragma unroll
      for (int I = 0; I < 16; ++I) {
        const int fb = frag_off(I);
        const int kcnt = (I + 2) >> 1;
        f32x4 a0 = {0.f,0.f,0.f,0.f}, a1 = {0.f,0.f,0.f,0.f}, a2 = {0.f,0.f,0.f,0.f};
#pragma unroll
        for (int kc = 0; kc < kcnt; ++kc) {
          const int fo = (fb + kc)*512 + lane*8;
          const short8 bh = *reinterpret_cast<const short8*>(bhB + fo);
          const short8 bl = *reinterpret_cast<const short8*>(blB + fo);
          const short8 br = *reinterpret_cast<const short8*>(brB + fo);
          a0 = __builtin_amdgcn_mfma_f32_16x16x32_bf16(ah[kc], bh, a0, 0, 0, 0);
          a0 = __builtin_amdgcn_mfma_f32_16x16x32_bf16(al[kc], bh, a0, 0, 0, 0);
          a0 = __builtin_amdgcn_mfma_f32_16x16x32_bf16(ar[kc], bh, a0, 0, 0, 0);
          a1 = __builtin_amdgcn_mfma_f32_16x16x32_bf16(ah[kc], bl, a1, 0, 0, 0);
          a1 = __builtin_amdgcn_mfma_f32_16x16x32_bf16(al[kc], bl, a1, 0, 0, 0);
          a2 = __builtin_amdgcn_mfma_f32_16x16x32_bf16(ah[kc], br, a2, 0, 0, 0);
        }
        const float t = tk[I*16 + li];
#pragma unroll
        for (int j = 0; j < 4; ++j) {
          const float y = a0[j] + a1[j] + a2[j];
          part[j] += y*(t - 0.5f*y);
        }
      }
#pragma unroll
      for (int mloc = 1; mloc < 16; mloc <<= 1) {
#pragma unroll
        for (int j = 0; j < 4; ++j) part[j] += __shfl_xor(part[j], mloc, 64);
      }
      const float bs = bias[k];
#pragma unroll
      for (int j = 0; j < 4; ++j) {
        const float sc = bs + part[j];
        if (sc > best[j]) { best[j] = sc; bk[j] = k; }
      }
    }

    if (li == 0) {
#pragma unroll
      for (int j = 0; j < 4; ++j) { lbest[w][h*4+j] = best[j]; lbk[w][h*4+j] = bk[j]; }
    }
    __syncthreads();
    if (tid < 16 && (sb + tid) < cnt) {
      float b = lbest[0][tid]; int k_ = lbk[0][tid];
#pragma unroll
      for (int ww = 1; ww < 4; ++ww)
        if (lbest[ww][tid] > b) { b = lbest[ww][tid]; k_ = lbk[ww][tid]; }
      out[flaglist[sb + tid]] = k_;
    }
    __syncthreads();
  }
}

extern "C" void kernel_launch(void* const* d_in, const int* in_sizes, int n_in,
                              void* d_out, int out_size, void* d_ws, size_t ws_size,
                              hipStream_t stream)
{
  const float* x   = (const float*)d_in[0];   // (8192, 256)
  const float* mu  = (const float*)d_in[1];   // (64, 256)
  const float* var = (const float*)d_in[2];   // (64, 256, 256)
  const float* pi  = (const float*)d_in[3];   // (64,)

  char* ws = (char*)d_ws;
  unsigned short* planes = (unsigned short*)ws;                      // 3 planes, 14.16 MB
  float* tvec = (float*)(ws + 3*PLANE_SH*sizeof(unsigned short));    // 64 KB
  float* bias = tvec + KC*D;                                         // 64 floats (pad to 256)
  float* partq = bias + 256;                                         // 8*8192*3 floats
  int* flaglist = (int*)(partq + (size_t)8*NPTS*3);                  // 8192 ints
  int* flagcnt = flaglist + NPTS;
  int* out = (int*)d_out;

  gmm_preproc<<<KC, 256, 0, stream>>>(var, mu, pi, planes, tvec, bias);
  gmm_score_mfma<<<512, 256, 0, stream>>>(x, planes, tvec, bias, partq);
  hipMemsetAsync(flagcnt, 0, sizeof(int), stream);
  gmm_merge<<<NPTS/256, 256, 0, stream>>>(partq, out, flaglist, flagcnt);
  gmm_exact<<<64, 256, 0, stream>>>(x, planes, tvec, bias, flaglist, flagcnt, out);
}

// Round 9
// 1173.171 us; speedup vs baseline: 2.9275x; 1.0534x over previous
//
#include <hip/hip_runtime.h>
#include <math.h>

#define D 256
#define KC 64
#define NPTS 8192
#define TRI ((D*(D+1))/2)

#define WSZ 33024             // odd-padded packed triangle size (floats)
#define FR_PER_CL 72          // triangular 16x16x32 fragments per cluster
#define SH_PER_CL (FR_PER_CL*512)           // shorts per cluster per plane
#define SLAB_SH ((size_t)(3*SH_PER_CL))     // shorts per cluster slab (3 planes)

typedef __attribute__((ext_vector_type(8))) short short8;
typedef __attribute__((ext_vector_type(4))) float f32x4;

__device__ __forceinline__ int wb(int r) { return (r*(r+1))/2 + (r>>1); }  // odd-padded row base
__device__ __forceinline__ unsigned short f2bf(float f) {                   // RNE float->bf16 bits
  unsigned u = __float_as_uint(f);
  u = (u + 0x7fffu + ((u >> 16) & 1u)) >> 16;
  return (unsigned short)u;
}
__device__ __forceinline__ float bf2f(unsigned short s) { return __uint_as_float(((unsigned)s) << 16); }
__device__ __forceinline__ float rdlane(float v, int l) {                   // force v_readlane path
  return __uint_as_float(__builtin_amdgcn_readlane(__float_as_uint(v), l));
}
// fragment offset table: off[I] = cumsum of kcnt(I')=(I'+2)>>1 ; closed form
__device__ __forceinline__ int frag_off(int I) { int a = I >> 1; return (I & 1) ? (a+1)*(a+1) : a*(a+1); }

// ---------------------------------------------------------------------------
// K1: factorization. Blocked Cholesky (register diag core with forced
// readlane broadcasts), TRSM, SYRK, blocked triangular inversion, t/bias.
// Writes the final packed G triangle (fp32, odd-padded, WSZ floats) into the
// head of this cluster's OWN plane slab (pack consumes it before overwrite).
// ---------------------------------------------------------------------------
__global__ __launch_bounds__(256, 1) void gmm_factor(
    const float* __restrict__ var, const float* __restrict__ mu,
    const float* __restrict__ pi,
    unsigned short* __restrict__ planes, float* __restrict__ tvec,
    float* __restrict__ bias)
{
  __shared__ float W[WSZ];        // packed lower triangle, odd-padded rows
  __shared__ float Tbuf[64*65];   // phase1: dense zero-padded U; phase2: T scratch
  __shared__ float colbuf[D];
  __shared__ float red[256];

  const int k = blockIdx.x, tid = threadIdx.x;
  const int lane = tid & 63, wid = tid >> 6;
  const float* A = var + (size_t)k*D*D;

  // ---- load packed lower triangle ----
  for (int idx = tid; idx < TRI; idx += 256) {
    int i = (int)((sqrtf(8.0f*(float)idx + 1.0f) - 1.0f)*0.5f);
    while ((i+1)*(i+2)/2 <= idx) ++i;
    while (i*(i+1)/2 > idx) --i;
    const int p = idx - i*(i+1)/2;
    W[wb(i) + p] = A[i*D + p];
  }
  __syncthreads();

  // ---- phase 1: blocked Cholesky, single-array register diag core ----
#pragma unroll 1
  for (int jb = 0; jb < 4; ++jb) {
    const int c0 = jb*64, c1 = c0 + 64, m = 256 - c1;

    if (wid == 0) {
      const int rbase = wb(c0 + lane) + c0;
      float Arow[64];
#pragma unroll
      for (int p = 0; p < 64; ++p) Arow[p] = W[rbase + p];   // p>lane: garbage, never escapes

      // in-register Cholesky (row per lane), readlane broadcasts
      float mydinv = 0.0f;
#pragma unroll
      for (int j = 0; j < 64; ++j) {
        const float dj = sqrtf(rdlane(Arow[j], j));
        const float dinv = 1.0f / dj;
        const float c = Arow[j] * dinv;           // valid for lane > j
        Arow[j] = (lane == j) ? dj : c;
        mydinv = (lane == j) ? dinv : mydinv;
#pragma unroll
        for (int p = j + 1; p < 64; ++p) {
          const float cp = rdlane(c, p);
          Arow[p] -= c * cp;                      // i==p updates diagonal; i<p garbage
        }
      }

      // G11 = inv(L11), forward substitution fused over the same array
#pragma unroll
      for (int p = 0; p < 64; ++p) {
        const float lp = (lane > p) ? Arow[p] : 0.0f;
#pragma unroll
        for (int j = 0; j < p; ++j) {
          const float fin = (0.0f - Arow[j]) * mydinv;
          Arow[j] = (lane == p) ? fin : Arow[j];
        }
        Arow[p] = (lane == p) ? mydinv : Arow[p];
#pragma unroll
        for (int j = 0; j < p; ++j) {
          const float gpj = rdlane(Arow[j], p);   // lane p's finalized G[p][j]
          Arow[j] += lp * gpj;
        }
        const float gpp = rdlane(Arow[p], p);     // = lane p's mydinv
        Arow[p] = (lane > p) ? (lp * gpp) : Arow[p];
      }

      // publish G11: packed W diag block (j<=lane) + dense zero-padded Tbuf
#pragma unroll
      for (int j = 0; j < 64; ++j) {
        if (j <= lane) W[rbase + j] = Arow[j];
        Tbuf[lane*65 + j] = (j <= lane) ? Arow[j] : 0.0f;
      }
    }
    __syncthreads();

    // TRSM: L21 = A21 * U^T via uniform LDS broadcasts
    if (tid < m) {
      const int rb = wb(c1 + tid) + c0;
      float row[64];
#pragma unroll
      for (int p = 0; p < 64; ++p) row[p] = W[rb + p];
      for (int j = 0; j < 64; ++j) {
        const float* up = &Tbuf[j*65];
        float a0 = 0.f, a1 = 0.f, a2 = 0.f, a3 = 0.f;
#pragma unroll
        for (int p = 0; p < 64; p += 4) {
          a0 += row[p]   * up[p];
          a1 += row[p+1] * up[p+1];
          a2 += row[p+2] * up[p+2];
          a3 += row[p+3] * up[p+3];
        }
        W[rb + j] = (a0 + a1) + (a2 + a3);
      }
    }
    __syncthreads();

    // SYRK: trailing triangle -= L21 * L21^T
    if (m > 0) {
      const int nt = m >> 2, ntri = nt*(nt+1)/2;
      for (int tau = tid; tau < ntri; tau += 256) {
        int ti = (int)((sqrtf(8.0f*(float)tau + 1.0f) - 1.0f)*0.5f);
        while ((ti+1)*(ti+2)/2 <= tau) ++ti;
        while (ti*(ti+1)/2 > tau) --ti;
        const int tl = tau - ti*(ti+1)/2;
        const int i0 = c1 + ti*4, l0 = c1 + tl*4;
        const int ib[4] = {wb(i0), wb(i0+1), wb(i0+2), wb(i0+3)};
        const int lb[4] = {wb(l0), wb(l0+1), wb(l0+2), wb(l0+3)};
        float acc[4][4];
#pragma unroll
        for (int a = 0; a < 4; ++a)
#pragma unroll
          for (int b = 0; b < 4; ++b) acc[a][b] = 0.0f;
        for (int p = 0; p < 64; ++p) {
          const int cp = c0 + p;
          float av[4], bv[4];
#pragma unroll
          for (int a = 0; a < 4; ++a) av[a] = W[ib[a] + cp];
#pragma unroll
          for (int b = 0; b < 4; ++b) bv[b] = W[lb[b] + cp];
#pragma unroll
          for (int a = 0; a < 4; ++a)
#pragma unroll
            for (int b = 0; b < 4; ++b) acc[a][b] += av[a]*bv[b];
        }
#pragma unroll
        for (int a = 0; a < 4; ++a)
#pragma unroll
          for (int b = 0; b < 4; ++b) {
            const int rr = i0 + a, cc = l0 + b;
            if (cc <= rr) W[ib[a] + cc] -= acc[a][b];
          }
      }
    }
    __syncthreads();
  }

  // ---- phase 2: blocked in-place inversion G = L^{-1} ----
  const int ti2 = tid >> 4, tj2 = tid & 15;
  const int i0g = ti2*4, j0g = tj2*4;
#pragma unroll 1
  for (int J = 0; J < 3; ++J) {
#pragma unroll 1
    for (int I = J + 1; I < 4; ++I) {
      float acc[4][4];
#pragma unroll
      for (int q = 0; q < 4; ++q)
#pragma unroll
        for (int r = 0; r < 4; ++r) acc[q][r] = 0.0f;
      for (int K = J; K < I; ++K) {
        const int arow = 64*I, brow = 64*K;
        const bool dK = (K == J);
        for (int p = 0; p < 64; ++p) {
          float av[4], bv[4];
#pragma unroll
          for (int q = 0; q < 4; ++q) av[q] = W[wb(arow + i0g + q) + 64*K + p];
#pragma unroll
          for (int r = 0; r < 4; ++r) {
            const float raw = W[wb(brow + p) + 64*J + j0g + r];
            bv[r] = (dK && (j0g + r > p)) ? 0.0f : raw;
          }
#pragma unroll
          for (int q = 0; q < 4; ++q)
#pragma unroll
            for (int r = 0; r < 4; ++r) acc[q][r] += av[q]*bv[r];
        }
      }
#pragma unroll
      for (int q = 0; q < 4; ++q)
#pragma unroll
        for (int r = 0; r < 4; ++r) Tbuf[(i0g+q)*65 + j0g + r] = acc[q][r];
      __syncthreads();

      float g[4][4];
#pragma unroll
      for (int q = 0; q < 4; ++q)
#pragma unroll
        for (int r = 0; r < 4; ++r) g[q][r] = 0.0f;
      for (int p = 0; p < 64; ++p) {
        float uv[4], tv4[4];
#pragma unroll
        for (int q = 0; q < 4; ++q) {
          const int ir = i0g + q;
          uv[q] = (p <= ir) ? W[wb(64*I + ir) + 64*I + p] : 0.0f;
        }
#pragma unroll
        for (int r = 0; r < 4; ++r) tv4[r] = Tbuf[p*65 + j0g + r];
#pragma unroll
        for (int q = 0; q < 4; ++q)
#pragma unroll
          for (int r = 0; r < 4; ++r) g[q][r] += uv[q]*tv4[r];
      }
      __syncthreads();
#pragma unroll
      for (int q = 0; q < 4; ++q)
#pragma unroll
        for (int r = 0; r < 4; ++r)
          W[wb(64*I + i0g + q) + 64*J + j0g + r] = -g[q][r];
      __syncthreads();
    }
  }

  // ---- phase 3: t = G*mu, bias ----
  colbuf[tid] = mu[k*D + tid];
  __syncthreads();
  {
    const int rb4 = wb(tid);
    float s = 0.0f;
    for (int p = 0; p <= tid; ++p) s += W[rb4 + p]*colbuf[p];
    tvec[k*D + tid] = s;
    red[tid] = s*s;
  }
  __syncthreads();
  for (int st = 128; st > 0; st >>= 1) { if (tid < st) red[tid] += red[tid+st]; __syncthreads(); }
  const float t2 = red[0];
  __syncthreads();
  red[tid] = logf(W[wb(tid) + tid]);
  __syncthreads();
  for (int st = 128; st > 0; st >>= 1) { if (tid < st) red[tid] += red[tid+st]; __syncthreads(); }
  if (tid == 0) bias[k] = logf(pi[k]) + red[0] - 0.5f*t2;
  __syncthreads();

  // ---- write packed fp32 G triangle into the head of this cluster's slab ----
  float* Wgk = (float*)(planes + (size_t)k*SLAB_SH);
  for (int idx = tid; idx < WSZ; idx += 256) Wgk[idx] = W[idx];
}

// ---------------------------------------------------------------------------
// K2: pack. Stage this cluster's fp32 triangle to LDS, then emit 3 bf16
// planes (hi/lo/r2) in MFMA B-fragment triangular layout, cluster-major,
// overwriting the slab (including the staged triangle -- safe after barrier).
// ---------------------------------------------------------------------------
__global__ __launch_bounds__(256, 1) void gmm_pack(unsigned short* __restrict__ planes)
{
  __shared__ float W[WSZ];
  const int k = blockIdx.x, tid = threadIdx.x;
  const float* Wgk = (const float*)(planes + (size_t)k*SLAB_SH);
  for (int idx = tid; idx < WSZ; idx += 256) W[idx] = Wgk[idx];
  __syncthreads();

  unsigned short* slab = planes + (size_t)k*SLAB_SH;
  for (int e = tid; e < SH_PER_CL; e += 256) {
    const int f = e >> 9, wrd = e & 511, l = wrd >> 3, j = wrd & 7;
    const int I = (f>=1)+(f>=2)+(f>=4)+(f>=6)+(f>=9)+(f>=12)+(f>=16)+(f>=20)
                +(f>=25)+(f>=30)+(f>=36)+(f>=42)+(f>=49)+(f>=56)+(f>=64);
    const int kc = f - frag_off(I);
    const int li = l & 15, hh = l >> 4;
    const int p = kc*32 + hh*8 + j, i2 = I*16 + li;
    const float g = (p <= i2) ? W[wb(i2) + p] : 0.0f;   // Gt[p][i] = G[i][p]
    const unsigned short hb = f2bf(g); const float hf = bf2f(hb);
    const float r1 = g - hf;
    const unsigned short lb = f2bf(r1); const float lf = bf2f(lb);
    const unsigned short rb = f2bf(r1 - lf);
    slab[e] = hb;
    slab[SH_PER_CL + e] = lb;
    slab[2*SH_PER_CL + e] = rb;
  }
}

// ---------------------------------------------------------------------------
// MFMA scoring: grid 256 = 32 n-tiles(256 pts) x 8 cluster-octants, 512 thr.
// 8 waves/block share each B-octant (halved distinct-fetch traffic).
// Split accumulators: acc_a = hh product, acc_b = lh+hl (independent chains).
// ---------------------------------------------------------------------------
__global__ __launch_bounds__(512, 1) void gmm_score_mfma(
    const float* __restrict__ x, const unsigned short* __restrict__ planes,
    const float* __restrict__ tvec, const float* __restrict__ bias,
    float* __restrict__ partq)
{
  const int tid = threadIdx.x, lane = tid & 63, w = tid >> 6;
  const int li = lane & 15, h = lane >> 4;
  const int ntile = blockIdx.x & 31, kq = blockIdx.x >> 5;
  const int n0 = ntile*256 + w*32;

  short8 ah[2][8], al[2][8];
#pragma unroll
  for (int s = 0; s < 2; ++s) {
    const float* xr = x + (size_t)(n0 + s*16 + li)*D;
#pragma unroll
    for (int kc = 0; kc < 8; ++kc) {
      const float4 v0 = *reinterpret_cast<const float4*>(xr + kc*32 + h*8);
      const float4 v1 = *reinterpret_cast<const float4*>(xr + kc*32 + h*8 + 4);
      const float xv[8] = {v0.x, v0.y, v0.z, v0.w, v1.x, v1.y, v1.z, v1.w};
#pragma unroll
      for (int j = 0; j < 8; ++j) {
        const unsigned short hb = f2bf(xv[j]);
        ah[s][kc][j] = (short)hb;
        al[s][kc][j] = (short)f2bf(xv[j] - bf2f(hb));
      }
    }
  }

  float best0[4], sec0[4], best1[4], sec1[4];
  int bk0[4], bk1[4];
#pragma unroll
  for (int j = 0; j < 4; ++j) {
    best0[j] = -3.0e38f; sec0[j] = -3.0e38f; bk0[j] = 0;
    best1[j] = -3.0e38f; sec1[j] = -3.0e38f; bk1[j] = 0;
  }

#pragma unroll 1
  for (int kk = 0; kk < 8; ++kk) {
    const int k = kq*8 + kk;
    const unsigned short* bhB = planes + (size_t)k*SLAB_SH;
    const unsigned short* blB = bhB + SH_PER_CL;
    const float* tk = tvec + k*D;
    float p0[4] = {0.f,0.f,0.f,0.f}, p1[4] = {0.f,0.f,0.f,0.f};
#pragma unroll
    for (int I = 0; I < 16; ++I) {
      const int fb = frag_off(I);
      const int kcnt = (I + 2) >> 1;
      f32x4 a0a = {0.f,0.f,0.f,0.f}, a0b = {0.f,0.f,0.f,0.f};
      f32x4 a1a = {0.f,0.f,0.f,0.f}, a1b = {0.f,0.f,0.f,0.f};
#pragma unroll
      for (int kc = 0; kc < kcnt; ++kc) {
        const int fo = (fb + kc)*512 + lane*8;
        const short8 bh = *reinterpret_cast<const short8*>(bhB + fo);
        const short8 bl = *reinterpret_cast<const short8*>(blB + fo);
        a0a = __builtin_amdgcn_mfma_f32_16x16x32_bf16(ah[0][kc], bh, a0a, 0, 0, 0);
        a1a = __builtin_amdgcn_mfma_f32_16x16x32_bf16(ah[1][kc], bh, a1a, 0, 0, 0);
        a0b = __builtin_amdgcn_mfma_f32_16x16x32_bf16(al[0][kc], bh, a0b, 0, 0, 0);
        a1b = __builtin_amdgcn_mfma_f32_16x16x32_bf16(al[1][kc], bh, a1b, 0, 0, 0);
        a0b = __builtin_amdgcn_mfma_f32_16x16x32_bf16(ah[0][kc], bl, a0b, 0, 0, 0);
        a1b = __builtin_amdgcn_mfma_f32_16x16x32_bf16(ah[1][kc], bl, a1b, 0, 0, 0);
      }
      const float t = tk[I*16 + li];
#pragma unroll
      for (int j = 0; j < 4; ++j) {
        float y = a0a[j] + a0b[j]; p0[j] += y*(t - 0.5f*y);
        y = a1a[j] + a1b[j];       p1[j] += y*(t - 0.5f*y);
      }
    }
#pragma unroll
    for (int mloc = 1; mloc < 16; mloc <<= 1) {
#pragma unroll
      for (int j = 0; j < 4; ++j) {
        p0[j] += __shfl_xor(p0[j], mloc, 64);
        p1[j] += __shfl_xor(p1[j], mloc, 64);
      }
    }
    const float bs = bias[k];
#pragma unroll
    for (int j = 0; j < 4; ++j) {
      const float s0v = bs + p0[j];
      if (s0v > best0[j]) { sec0[j] = best0[j]; best0[j] = s0v; bk0[j] = k; }
      else if (s0v > sec0[j]) sec0[j] = s0v;
      const float s1v = bs + p1[j];
      if (s1v > best1[j]) { sec1[j] = best1[j]; best1[j] = s1v; bk1[j] = k; }
      else if (s1v > sec1[j]) sec1[j] = s1v;
    }
  }

  if (li == 0) {
#pragma unroll
    for (int j = 0; j < 4; ++j) {
      const size_t r0 = ((size_t)kq*NPTS + n0 + h*4 + j)*3;
      partq[r0] = best0[j]; partq[r0+1] = __int_as_float(bk0[j]); partq[r0+2] = sec0[j];
      const size_t r1 = ((size_t)kq*NPTS + n0 + 16 + h*4 + j)*3;
      partq[r1] = best1[j]; partq[r1+1] = __int_as_float(bk1[j]); partq[r1+2] = sec1[j];
    }
  }
}

// ---------------------------------------------------------------------------
// Merge 8 octants; flag small-margin points for exact re-scoring.
// ---------------------------------------------------------------------------
__global__ __launch_bounds__(256) void gmm_merge(
    const float* __restrict__ partq, int* __restrict__ out,
    int* __restrict__ flaglist, int* __restrict__ flagcnt)
{
  const int n = blockIdx.x*256 + threadIdx.x;
  float b = -3.0e38f, s2 = -3.0e38f; int bk = 0;
#pragma unroll
  for (int q = 0; q < 8; ++q) {
    const size_t o = ((size_t)q*NPTS + n)*3;
    const float bq = partq[o];
    const int kq_ = __float_as_int(partq[o+1]);
    const float sq = partq[o+2];
    if (bq > b) { s2 = fmaxf(b, sq); b = bq; bk = kq_; }
    else        { s2 = fmaxf(s2, bq); }
  }
  out[n] = bk;
  if (b - s2 < 0.25f) {
    const int idx = atomicAdd(flagcnt, 1);
    flaglist[idx] = n;
  }
}

// ---------------------------------------------------------------------------
// Exact (split-3 x split-3 truncated, ~2^-24) re-score of flagged points.
// ---------------------------------------------------------------------------
__global__ __launch_bounds__(256) void gmm_exact(
    const float* __restrict__ x, const unsigned short* __restrict__ planes,
    const float* __restrict__ tvec, const float* __restrict__ bias,
    const int* __restrict__ flaglist, const int* __restrict__ flagcnt,
    int* __restrict__ out)
{
  __shared__ float lbest[4][16];
  __shared__ int   lbk[4][16];
  const int tid = threadIdx.x, lane = tid & 63, w = tid >> 6;
  const int li = lane & 15, h = lane >> 4;
  const int cnt = *flagcnt;

#pragma unroll 1
  for (int sb = blockIdx.x*16; sb < cnt; sb += gridDim.x*16) {
    const int slot = sb + li;
    const int row = (slot < cnt) ? flaglist[slot] : 0;

    short8 ah[8], al[8], ar[8];
    const float* xr = x + (size_t)row*D;
#pragma unroll
    for (int kc = 0; kc < 8; ++kc) {
      const float4 v0 = *reinterpret_cast<const float4*>(xr + kc*32 + h*8);
      const float4 v1 = *reinterpret_cast<const float4*>(xr + kc*32 + h*8 + 4);
      const float xv[8] = {v0.x, v0.y, v0.z, v0.w, v1.x, v1.y, v1.z, v1.w};
#pragma unroll
      for (int j = 0; j < 8; ++j) {
        const unsigned short hb = f2bf(xv[j]); const float hf = bf2f(hb);
        const float r1 = xv[j] - hf;
        const unsigned short lb = f2bf(r1); const float lf = bf2f(lb);
        ah[kc][j] = (short)hb; al[kc][j] = (short)lb; ar[kc][j] = (short)f2bf(r1 - lf);
      }
    }

    float best[4]; int bk[4];
#pragma unroll
    for (int j = 0; j < 4; ++j) { best[j] = -3.0e38f; bk[j] = 0; }

#pragma unroll 1
    for (int kk = 0; kk < 16; ++kk) {
      const int k = w*16 + kk;
      const unsigned short* bhB = planes + (size_t)k*SLAB_SH;
      const unsigned short* blB = bhB + SH_PER_CL;
      const unsigned short* brB = bhB + 2*SH_PER_CL;
      const float* tk = tvec + k*D;
      float part[4] = {0.f,0.f,0.f,0.f};
#pragma unroll
      for (int I = 0; I < 16; ++I) {
        const int fb = frag_off(I);
        const int kcnt = (I + 2) >> 1;
        f32x4 a0 = {0.f,0.f,0.f,0.f}, a1 = {0.f,0.f,0.f,0.f}, a2 = {0.f,0.f,0.f,0.f};
#pragma unroll
        for (int kc = 0; kc < kcnt; ++kc) {
          const int fo = (fb + kc)*512 + lane*8;
          const short8 bh = *reinterpret_cast<const short8*>(bhB + fo);
          const short8 bl = *reinterpret_cast<const short8*>(blB + fo);
          const short8 br = *reinterpret_cast<const short8*>(brB + fo);
          a0 = __builtin_amdgcn_mfma_f32_16x16x32_bf16(ah[kc], bh, a0, 0, 0, 0);
          a0 = __builtin_amdgcn_mfma_f32_16x16x32_bf16(al[kc], bh, a0, 0, 0, 0);
          a0 = __builtin_amdgcn_mfma_f32_16x16x32_bf16(ar[kc], bh, a0, 0, 0, 0);
          a1 = __builtin_amdgcn_mfma_f32_16x16x32_bf16(ah[kc], bl, a1, 0, 0, 0);
          a1 = __builtin_amdgcn_mfma_f32_16x16x32_bf16(al[kc], bl, a1, 0, 0, 0);
          a2 = __builtin_amdgcn_mfma_f32_16x16x32_bf16(ah[kc], br, a2, 0, 0, 0);
        }
        const float t = tk[I*16 + li];
#pragma unroll
        for (int j = 0; j < 4; ++j) {
          const float y = a0[j] + a1[j] + a2[j];
          part[j] += y*(t - 0.5f*y);
        }
      }
#pragma unroll
      for (int mloc = 1; mloc < 16; mloc <<= 1) {
#pragma unroll
        for (int j = 0; j < 4; ++j) part[j] += __shfl_xor(part[j], mloc, 64);
      }
      const float bs = bias[k];
#pragma unroll
      for (int j = 0; j < 4; ++j) {
        const float sc = bs + part[j];
        if (sc > best[j]) { best[j] = sc; bk[j] = k; }
      }
    }

    if (li == 0) {
#pragma unroll
      for (int j = 0; j < 4; ++j) { lbest[w][h*4+j] = best[j]; lbk[w][h*4+j] = bk[j]; }
    }
    __syncthreads();
    if (tid < 16 && (sb + tid) < cnt) {
      float b = lbest[0][tid]; int k_ = lbk[0][tid];
#pragma unroll
      for (int ww = 1; ww < 4; ++ww)
        if (lbest[ww][tid] > b) { b = lbest[ww][tid]; k_ = lbk[ww][tid]; }
      out[flaglist[sb + tid]] = k_;
    }
    __syncthreads();
  }
}

extern "C" void kernel_launch(void* const* d_in, const int* in_sizes, int n_in,
                              void* d_out, int out_size, void* d_ws, size_t ws_size,
                              hipStream_t stream)
{
  const float* x   = (const float*)d_in[0];   // (8192, 256)
  const float* mu  = (const float*)d_in[1];   // (64, 256)
  const float* var = (const float*)d_in[2];   // (64, 256, 256)
  const float* pi  = (const float*)d_in[3];   // (64,)

  char* ws = (char*)d_ws;
  unsigned short* planes = (unsigned short*)ws;                      // 64 cluster slabs, 14.16 MB
  float* tvec = (float*)(ws + KC*SLAB_SH*sizeof(unsigned short));    // 64 KB
  float* bias = tvec + KC*D;                                         // 64 floats (pad to 256)
  float* partq = bias + 256;                                         // 8*8192*3 floats
  int* flaglist = (int*)(partq + (size_t)8*NPTS*3);                  // 8192 ints
  int* flagcnt = flaglist + NPTS;
  int* out = (int*)d_out;

  gmm_factor<<<KC, 256, 0, stream>>>(var, mu, pi, planes, tvec, bias);
  gmm_pack<<<KC, 256, 0, stream>>>(planes);
  gmm_score_mfma<<<256, 512, 0, stream>>>(x, planes, tvec, bias, partq);
  hipMemsetAsync(flagcnt, 0, sizeof(int), stream);
  gmm_merge<<<NPTS/256, 256, 0, stream>>>(partq, out, flaglist, flagcnt);
  gmm_exact<<<64, 256, 0, stream>>>(x, planes, tvec, bias, flaglist, flagcnt, out);
}